// Round 1
// 383.285 us; speedup vs baseline: 1.0186x; 1.0186x over previous
//
#include <hip/hip_runtime.h>

typedef unsigned int u32;
typedef _Float16 f16;
typedef __attribute__((ext_vector_type(8))) _Float16 half8;
typedef __attribute__((ext_vector_type(2))) _Float16 half2_t;
typedef __attribute__((ext_vector_type(4))) float f32x4;

#define D_IN 128
#define D_HID 128
#define D_OUT 16
#define RPB 128        // rows per bucket (lr fits in 7 bits; c < 2^20)
#define MAXBUCK 1024   // supports N <= 131072
#define CHUNK 16384    // edges per hist/scatter block (256 thr x 64)
#define PGRAN 4        // pad each row's edge run to a multiple of 4 (R12: was
                       // 16 -> 43% sentinel gathers; 4 -> ~9%, keeps 16B align)
#define SLACK 2048     // per-bucket capacity bonus; mult of 16, >= 128*3+15

// ---------------- preprocessing ----------------

// flag: 1 if edge_index is int32 layout, 0 if int64 (odd words all zero).
__global__ __launch_bounds__(256) void detect_k(const int* __restrict__ ei,
                                                u32* __restrict__ flag, int n) {
    int i = blockIdx.x * 256 + threadIdx.x;
    if (i < n && (i & 1) && ei[i] != 0) atomicOr(flag, 1u);
}

__device__ inline int load_row(const int* ei, u32 f, int e, int E) {
    return f ? ei[e] : ei[2 * e];
}
__device__ inline int load_col(const int* ei, u32 f, int e, int E) {
    return f ? ei[E + e] : ei[2 * E + 2 * e];
}
__device__ inline int clampi(int v, int n) {
    v = v < 0 ? 0 : v;
    return v >= n ? n - 1 : v;
}
__device__ inline u32 al16(u32 v) { return (v + 15u) & ~15u; }

// Pass 1: per-block histogram over row-buckets (bucket-major Hmat, plain
// stores — no global atomics at all).
__global__ __launch_bounds__(256) void hist_k(const int* __restrict__ ei,
                                              const u32* __restrict__ flag,
                                              u32* __restrict__ Hmat,
                                              int E, int N, int NBK, int NB) {
    __shared__ u32 lh[MAXBUCK];
    int tid = threadIdx.x;
    for (int i = tid; i < NBK; i += 256) lh[i] = 0;
    __syncthreads();
    u32 f = *flag;
    int base = blockIdx.x * CHUNK;
    int lim = base + CHUNK < E ? base + CHUNK : E;
    for (int e = base + tid; e < lim; e += 256) {
        int r = clampi(load_row(ei, f, e, E), N);
        atomicAdd(&lh[(u32)r >> 7], 1u);
    }
    __syncthreads();
    for (int i = tid; i < NBK; i += 256)
        Hmat[(size_t)i * NB + blockIdx.x] = lh[i];
}

__global__ __launch_bounds__(256) void scan1(const u32* __restrict__ cnt,
                                             u32* __restrict__ excl,
                                             u32* __restrict__ partial, int n) {
    __shared__ u32 sm[256];
    int tid = threadIdx.x;
    int i = blockIdx.x * 256 + tid;
    u32 v = (i < n) ? cnt[i] : 0u;
    sm[tid] = v;
    __syncthreads();
    for (int off = 1; off < 256; off <<= 1) {
        u32 t = (tid >= off) ? sm[tid - off] : 0u;
        __syncthreads();
        sm[tid] += t;
        __syncthreads();
    }
    if (i < n) excl[i] = sm[tid] - v;
    if (tid == 255) partial[blockIdx.x] = sm[255];
}

__global__ __launch_bounds__(512) void scan2(u32* __restrict__ partial, int nb) {
    __shared__ u32 sm[512];
    int tid = threadIdx.x;
    u32 v = (tid < nb) ? partial[tid] : 0u;
    sm[tid] = v;
    __syncthreads();
    for (int off = 1; off < 512; off <<= 1) {
        u32 t = (tid >= off) ? sm[tid - off] : 0u;
        __syncthreads();
        sm[tid] += t;
        __syncthreads();
    }
    if (tid < nb) partial[tid] = sm[tid] - v;
}

__global__ __launch_bounds__(256) void scan3(u32* __restrict__ excl,
                                             const u32* __restrict__ partial,
                                             int n, int E) {
    int i = blockIdx.x * 256 + threadIdx.x;
    if (i < n) excl[i] += partial[blockIdx.x];
    if (i == 0) excl[n] = (u32)E;
}

// Pass 2: re-read edges; block-exact frontiers per bucket (from scanned Hmat),
// only LDS atomics. Record = (r&127)<<20 | c (u32, c < 2^20).
__global__ __launch_bounds__(256) void scatter_bd(const int* __restrict__ ei,
                                                  const u32* __restrict__ flag,
                                                  const u32* __restrict__ Hbase,
                                                  u32* __restrict__ bdata,
                                                  int E, int N, int NBK, int NB) {
    __shared__ u32 lbase[MAXBUCK];
    int tid = threadIdx.x;
    for (int i = tid; i < NBK; i += 256)
        lbase[i] = Hbase[(size_t)i * NB + blockIdx.x];
    __syncthreads();
    u32 f = *flag;
    int base = blockIdx.x * CHUNK;
    int lim = base + CHUNK < E ? base + CHUNK : E;
    for (int e = base + tid; e < lim; e += 256) {
        int r = clampi(load_row(ei, f, e, E), N);
        int c = clampi(load_col(ei, f, e, E), N);
        u32 pos = atomicAdd(&lbase[(u32)r >> 7], 1u);
        if (pos < (u32)E) bdata[pos] = ((u32)(r & (RPB - 1)) << 20) | (u32)c;
    }
}

// Pass 3: PADDED CSR with EXPLICIT per-row ends. Each row r gets
// [row_start[r], rend[r]) with rend-beg = pdeg (mult of PGRAN, pad -> sentinel
// col N). Bucket slack is NEVER scanned (R11 bug: last row of each bucket
// inherited the slack via row_start[r+1], and those every-32nd-block
// stragglers all resonated onto one XCD -> 7.7% occupancy, 557us).
__global__ __launch_bounds__(256) void finalize_k(const u32* __restrict__ bdata,
                                                  const u32* __restrict__ Hbase,
                                                  u32* __restrict__ row_start,
                                                  u32* __restrict__ rend,
                                                  float* __restrict__ dinv,
                                                  u32* __restrict__ ecol,
                                                  int N, int E, int NB) {
    __shared__ u32 smc[RPB];
    __shared__ u32 cur[RPB];
    int b = blockIdx.x;
    int tid = threadIdx.x;
    u32 s = Hbase[(size_t)b * NB];
    u32 t = Hbase[(size_t)(b + 1) * NB];  // last bucket hits sentinel = E
    u32 pbase = al16(s) + (u32)b * SLACK;
    if (tid < RPB) smc[tid] = 0;
    __syncthreads();
    for (u32 i = s + tid; i < t; i += 256)
        atomicAdd(&smc[bdata[i] >> 20], 1u);
    __syncthreads();
    u32 deg = (tid < RPB) ? smc[tid] : 0;
    u32 pdeg = (deg + PGRAN - 1) & ~(u32)(PGRAN - 1);
    if (tid < RPB) smc[tid] = pdeg;
    __syncthreads();
    for (int off = 1; off < RPB; off <<= 1) {
        u32 tv = (tid < RPB && tid >= off) ? smc[tid - off] : 0u;
        __syncthreads();
        if (tid < RPB) smc[tid] += tv;
        __syncthreads();
    }
    u32 pexcl = (tid < RPB) ? (smc[tid] - pdeg) : 0;
    if (tid < RPB) {
        int r = b * RPB + tid;
        if (r < N) {
            row_start[r] = pbase + pexcl;
            rend[r] = pbase + pexcl + pdeg;
            dinv[r] = rsqrtf((float)(deg + 1u));  // +1 self loop
        }
        cur[tid] = pbase + pexcl;
    }
    __syncthreads();
    for (u32 i = s + tid; i < t; i += 256) {
        u32 rec = bdata[i];
        u32 pos = atomicAdd(&cur[rec >> 20], 1u);
        ecol[pos] = rec & 0xFFFFFu;
    }
    __syncthreads();
    if (tid < RPB) {  // per-row pad tail -> sentinel zero-row
        u32 st = pbase + pexcl;
        for (u32 k = deg; k < pdeg; k++) ecol[st + k] = (u32)N;
    }
    // bucket slack never read (rend bounds every row) -> no fill needed.
}

// Split fp32 W into hi/lo f16 MFMA B-fragments. Blocks 0-7 -> W1, 8-15 -> W2,
// 16 -> W3, 17 -> zero the sentinel rows h[N], h3[N].
__global__ __launch_bounds__(256) void reformat_all(const float* __restrict__ W1,
                                                    const float* __restrict__ W2,
                                                    const float* __restrict__ W3,
                                                    f16* __restrict__ W1h, f16* __restrict__ W1l,
                                                    f16* __restrict__ W2h, f16* __restrict__ W2l,
                                                    f16* __restrict__ W3h, f16* __restrict__ W3l,
                                                    f16* __restrict__ hzero,
                                                    f16* __restrict__ h3zero) {
    if (blockIdx.x == 17) {
        int tix = threadIdx.x;
        if (tix < 128) hzero[tix] = (f16)0;
        else if (tix < 144) h3zero[tix - 128] = (f16)0;
        return;
    }
    const float* W;
    f16 *Wh, *Wl;
    int ntiles, bidx;
    if (blockIdx.x < 8) { W = W1; Wh = W1h; Wl = W1l; ntiles = 8; bidx = blockIdx.x; }
    else if (blockIdx.x < 16) { W = W2; Wh = W2h; Wl = W2l; ntiles = 8; bidx = blockIdx.x - 8; }
    else { W = W3; Wh = W3h; Wl = W3l; ntiles = 1; bidx = 0; }
    int idx = bidx * 256 + threadIdx.x;
    int total = 4 * ntiles * 64;
    if (idx >= total) return;
    int lane = idx & 63;
    int st = idx >> 6;
    int t = st % ntiles;
    int s = st / ntiles;
    int Nc = ntiles * 16;
    int n = t * 16 + (lane & 15);
    int kb = lane >> 4;
    half8 vh, vl;
#pragma unroll
    for (int j = 0; j < 8; j++) {
        float w = W[(size_t)(s * 32 + kb * 8 + j) * Nc + n];
        f16 hi = (f16)w;
        f16 lo = (f16)(w - (float)hi);
        vh[j] = hi;
        vl[j] = lo;
    }
    *(half8*)(Wh + (size_t)idx * 8) = vh;
    *(half8*)(Wl + (size_t)idx * 8) = vl;
}

// ---------------- GEMMs (f16 MFMA 16x16x32, fp32-accurate via splits) --------

// Layer 1: A fp32 [M x 128]; 3 MFMAs; epilogue scales row rr by dinv[rr]
// so the stored table is h' = (x@W1)*dinv  (norm folded into storage).
__global__ __launch_bounds__(256) void gemm128_l1(const float* __restrict__ A,
                                                  const f16* __restrict__ Wh,
                                                  const f16* __restrict__ Wl,
                                                  const float* __restrict__ dinv,
                                                  f16* __restrict__ H, int M) {
    int wave = threadIdx.x >> 6, lane = threadIdx.x & 63;
    int mbase = blockIdx.x * 64 + wave * 16;
    int mload = mbase + (lane & 15);
    if (mload >= M) mload = M - 1;
    int kq = lane >> 4;
    f32x4 acc[8];
#pragma unroll
    for (int t = 0; t < 8; t++) acc[t] = (f32x4){0.f, 0.f, 0.f, 0.f};
#pragma unroll
    for (int s = 0; s < 4; s++) {
        const float* ap = A + (size_t)mload * 128 + s * 32 + kq * 8;
        half8 ah, al;
#pragma unroll
        for (int j = 0; j < 8; j++) {
            float v = ap[j];
            f16 hi = (f16)v;
            ah[j] = hi;
            al[j] = (f16)(v - (float)hi);
        }
#pragma unroll
        for (int t = 0; t < 8; t++) {
            half8 bh = *(const half8*)(Wh + (size_t)((s * 8 + t) * 64 + lane) * 8);
            half8 bl = *(const half8*)(Wl + (size_t)((s * 8 + t) * 64 + lane) * 8);
            acc[t] = __builtin_amdgcn_mfma_f32_16x16x32_f16(ah, bh, acc[t], 0, 0, 0);
            acc[t] = __builtin_amdgcn_mfma_f32_16x16x32_f16(ah, bl, acc[t], 0, 0, 0);
            acc[t] = __builtin_amdgcn_mfma_f32_16x16x32_f16(al, bh, acc[t], 0, 0, 0);
        }
    }
    int coln = lane & 15;
    int rbase = mbase + ((lane >> 4) << 2);
    float dsc[4];
#pragma unroll
    for (int i = 0; i < 4; i++) {
        int rr = rbase + i;
        dsc[i] = dinv[rr < M ? rr : M - 1];
    }
#pragma unroll
    for (int t = 0; t < 8; t++) {
#pragma unroll
        for (int i = 0; i < 4; i++) {
            int rr = rbase + i;
            if (rr < M) H[(size_t)rr * 128 + t * 16 + coln] = (f16)(acc[t][i] * dsc[i]);
        }
    }
}

// Layer 2: A f16 (pre-scaled act') [M x 128]; 2 MFMAs; output inherits the
// dinv row-scale automatically ((act*dinv)@W = (act@W)*dinv).
__global__ __launch_bounds__(256) void gemm128_l2(const f16* __restrict__ A,
                                                  const f16* __restrict__ Wh,
                                                  const f16* __restrict__ Wl,
                                                  f16* __restrict__ H, int M) {
    int wave = threadIdx.x >> 6, lane = threadIdx.x & 63;
    int mbase = blockIdx.x * 64 + wave * 16;
    int mload = mbase + (lane & 15);
    if (mload >= M) mload = M - 1;
    int kq = lane >> 4;
    f32x4 acc[8];
#pragma unroll
    for (int t = 0; t < 8; t++) acc[t] = (f32x4){0.f, 0.f, 0.f, 0.f};
#pragma unroll
    for (int s = 0; s < 4; s++) {
        half8 a = *(const half8*)(A + (size_t)mload * 128 + s * 32 + kq * 8);
#pragma unroll
        for (int t = 0; t < 8; t++) {
            half8 bh = *(const half8*)(Wh + (size_t)((s * 8 + t) * 64 + lane) * 8);
            half8 bl = *(const half8*)(Wl + (size_t)((s * 8 + t) * 64 + lane) * 8);
            acc[t] = __builtin_amdgcn_mfma_f32_16x16x32_f16(a, bh, acc[t], 0, 0, 0);
            acc[t] = __builtin_amdgcn_mfma_f32_16x16x32_f16(a, bl, acc[t], 0, 0, 0);
        }
    }
    int coln = lane & 15;
    int rbase = mbase + ((lane >> 4) << 2);
#pragma unroll
    for (int t = 0; t < 8; t++) {
#pragma unroll
        for (int i = 0; i < 4; i++) {
            int rr = rbase + i;
            if (rr < M) H[(size_t)rr * 128 + t * 16 + coln] = (f16)acc[t][i];
        }
    }
}

// Layer 3: A f16 (pre-scaled) [M x 128] -> H3' f16 [M x 16].
__global__ __launch_bounds__(256) void gemm16(const f16* __restrict__ A,
                                              const f16* __restrict__ Wh,
                                              const f16* __restrict__ Wl,
                                              f16* __restrict__ H, int M) {
    int wave = threadIdx.x >> 6, lane = threadIdx.x & 63;
    int mbase = blockIdx.x * 64 + wave * 16;
    int mload = mbase + (lane & 15);
    if (mload >= M) mload = M - 1;
    int kq = lane >> 4;
    f32x4 acc = (f32x4){0.f, 0.f, 0.f, 0.f};
#pragma unroll
    for (int s = 0; s < 4; s++) {
        half8 a = *(const half8*)(A + (size_t)mload * 128 + s * 32 + kq * 8);
        half8 bh = *(const half8*)(Wh + (size_t)(s * 64 + lane) * 8);
        half8 bl = *(const half8*)(Wl + (size_t)(s * 64 + lane) * 8);
        acc = __builtin_amdgcn_mfma_f32_16x16x32_f16(a, bh, acc, 0, 0, 0);
        acc = __builtin_amdgcn_mfma_f32_16x16x32_f16(a, bl, acc, 0, 0, 0);
    }
    int coln = lane & 15;
    int rbase = mbase + ((lane >> 4) << 2);
#pragma unroll
    for (int i = 0; i < 4; i++) {
        int rr = rbase + i;
        if (rr < M) H[(size_t)rr * 16 + coln] = (f16)acc[i];
    }
}

// ---------------- aggregation ----------------
// One wave per row; lane handles features 2*lane, 2*lane+1 (half2, 4B/lane ->
// one coalesced 256B gather per edge). R12: (a) readfirstlane forces beg/end/
// ecol uniform -> s_load_dwordx4 batches instead of 16 vector loads + 64b addr
// math; (b) gathers via u32 offset from SGPR base (saddr form, 1 VALU each);
// (c) accumulate with fmaf(v, dinv, acc) -> v_fma_mix_f32 folds the f16 cvt
// and the row scale into one op (single-rounding, numerics same-or-better);
// (d) PGRAN=4 -> 16-batch main loop + 4-batch tail, ~24% fewer gathers.
__global__ __launch_bounds__(256) void agg128(const f16* __restrict__ h,
                                              const u32* __restrict__ ecol,
                                              const u32* __restrict__ row_start,
                                              const u32* __restrict__ rend,
                                              const float* __restrict__ dinv,
                                              const float* __restrict__ bias,
                                              f16* __restrict__ out, int M) {
    int lane = threadIdx.x & 63;
    int wave = __builtin_amdgcn_readfirstlane(threadIdx.x >> 6);
    int r = blockIdx.x * 4 + wave;
    if (r >= M) return;
    u32 beg = (u32)__builtin_amdgcn_readfirstlane((int)row_start[r]);
    u32 end = (u32)__builtin_amdgcn_readfirstlane((int)rend[r]);
    float dr = dinv[r];
    const char* hb = (const char*)h;
    u32 loff = (u32)lane << 2;
    float ax0 = 0, ay0 = 0, ax1 = 0, ay1 = 0, ax2 = 0, ay2 = 0, ax3 = 0, ay3 = 0;
    u32 e = beg;
    for (; e + 16 <= end; e += 16) {
        const u32* ep = ecol + e;
        u32 c[16];
#pragma unroll
        for (int j = 0; j < 16; j++) c[j] = ep[j];
        half2_t v[16];
#pragma unroll
        for (int j = 0; j < 16; j++)
            v[j] = *(const half2_t*)(hb + ((c[j] << 8) + loff));
#pragma unroll
        for (int j = 0; j < 16; j += 4) {
            ax0 = fmaf((float)v[j][0],     dr, ax0); ay0 = fmaf((float)v[j][1],     dr, ay0);
            ax1 = fmaf((float)v[j + 1][0], dr, ax1); ay1 = fmaf((float)v[j + 1][1], dr, ay1);
            ax2 = fmaf((float)v[j + 2][0], dr, ax2); ay2 = fmaf((float)v[j + 2][1], dr, ay2);
            ax3 = fmaf((float)v[j + 3][0], dr, ax3); ay3 = fmaf((float)v[j + 3][1], dr, ay3);
        }
    }
    for (; e < end; e += 4) {  // tail: 0-3 iterations of 4 (pdeg mult of 4)
        const u32* ep = ecol + e;
        u32 c0 = ep[0], c1 = ep[1], c2 = ep[2], c3 = ep[3];
        half2_t v0 = *(const half2_t*)(hb + ((c0 << 8) + loff));
        half2_t v1 = *(const half2_t*)(hb + ((c1 << 8) + loff));
        half2_t v2 = *(const half2_t*)(hb + ((c2 << 8) + loff));
        half2_t v3 = *(const half2_t*)(hb + ((c3 << 8) + loff));
        ax0 = fmaf((float)v0[0], dr, ax0); ay0 = fmaf((float)v0[1], dr, ay0);
        ax1 = fmaf((float)v1[0], dr, ax1); ay1 = fmaf((float)v1[1], dr, ay1);
        ax2 = fmaf((float)v2[0], dr, ax2); ay2 = fmaf((float)v2[1], dr, ay2);
        ax3 = fmaf((float)v3[0], dr, ax3); ay3 = fmaf((float)v3[1], dr, ay3);
    }
    half2_t vs = *(const half2_t*)(hb + (((u32)r << 8) + loff));
    float2 bb = ((const float2*)bias)[lane];
    float ax = ((ax0 + ax1) + (ax2 + ax3)) + fmaf((float)vs[0], dr, bb.x);
    float ay = ((ay0 + ay1) + (ay2 + ay3)) + fmaf((float)vs[1], dr, bb.y);
    ax = fmaxf(ax, 0.f) * dr;  // pre-scale for next layer's gather
    ay = fmaxf(ay, 0.f) * dr;
    half2_t o;
    o[0] = (f16)ax;
    o[1] = (f16)ay;
    ((half2_t*)out)[(size_t)r * 64 + lane] = o;
}

// 16 lanes per row; h3' pre-scaled; padded CSR (PGRAN=4) -> 8-batches + one
// optional 4-batch tail, no scalar tail.
__global__ __launch_bounds__(256) void agg16_lsm(const f16* __restrict__ h3,
                                                 const u32* __restrict__ ecol,
                                                 const u32* __restrict__ row_start,
                                                 const u32* __restrict__ rend,
                                                 const float* __restrict__ dinv,
                                                 const float* __restrict__ bias,
                                                 float* __restrict__ out, int M) {
    int g = threadIdx.x >> 4, l = threadIdx.x & 15;
    int r = blockIdx.x * 16 + g;
    if (r >= M) return;
    u32 beg = row_start[r], end = rend[r];
    float a0 = 0.f, a1 = 0.f, a2 = 0.f, a3 = 0.f;
    u32 e = beg;
    for (; e + 8 <= end; e += 8) {
        u32 c[8];
#pragma unroll
        for (int j = 0; j < 8; j++) c[j] = ecol[e + j];
        f16 v[8];
#pragma unroll
        for (int j = 0; j < 8; j++) v[j] = h3[(size_t)c[j] * 16 + l];
        a0 += (float)v[0] + (float)v[4];
        a1 += (float)v[1] + (float)v[5];
        a2 += (float)v[2] + (float)v[6];
        a3 += (float)v[3] + (float)v[7];
    }
    if (e < end) {  // remainder is exactly 4
        u32 c[4];
#pragma unroll
        for (int j = 0; j < 4; j++) c[j] = ecol[e + j];
        f16 v[4];
#pragma unroll
        for (int j = 0; j < 4; j++) v[j] = h3[(size_t)c[j] * 16 + l];
        a0 += (float)v[0];
        a1 += (float)v[1];
        a2 += (float)v[2];
        a3 += (float)v[3];
    }
    float dr = dinv[r];
    float acc = (((a0 + a1) + (a2 + a3)) + (float)h3[(size_t)r * 16 + l]) * dr +
                bias[l];
    float m = acc;
#pragma unroll
    for (int o = 8; o >= 1; o >>= 1) m = fmaxf(m, __shfl_xor(m, o, 16));
    float ex = expf(acc - m);
    float s = ex;
#pragma unroll
    for (int o = 8; o >= 1; o >>= 1) s += __shfl_xor(s, o, 16);
    out[(size_t)r * 16 + l] = acc - m - logf(s);
}

// ---------------- launch ----------------

extern "C" void kernel_launch(void* const* d_in, const int* in_sizes, int n_in,
                              void* d_out, int out_size, void* d_ws, size_t ws_size,
                              hipStream_t stream) {
    const float* x = (const float*)d_in[0];
    const int* ei = (const int*)d_in[1];
    const float* W1 = (const float*)d_in[2];
    const float* b1 = (const float*)d_in[3];
    const float* W2 = (const float*)d_in[4];
    const float* b2 = (const float*)d_in[5];
    const float* W3 = (const float*)d_in[6];
    const float* b3 = (const float*)d_in[7];
    int N = in_sizes[0] / D_IN;
    int E = in_sizes[1] / 2;

    int NBK = (N + RPB - 1) / RPB;     // 782 row-buckets (<= MAXBUCK)
    int NB = (E + CHUNK - 1) / CHUNK;  // 98 hist/scatter blocks
    int L = NBK * NB;                  // 76636 Hmat entries
    size_t Epad = ((size_t)E + 16) + (size_t)NBK * SLACK + 256;

    char* p = (char*)d_ws;
    auto alloc = [&](size_t bytes) -> void* {
        void* q = (void*)p;
        p += (bytes + 255) & ~(size_t)255;
        return q;
    };
    u32* flag = (u32*)alloc(256);
    float* dinv = (float*)alloc((size_t)N * 4);
    u32* row_start = (u32*)alloc((size_t)(N + 1) * 4);
    u32* rend = (u32*)alloc((size_t)N * 4);
    u32* partial2 = (u32*)alloc(4096);
    u32* Hmat = (u32*)alloc((size_t)(L + 1) * 4);
    u32* ecol = (u32*)alloc(Epad * 4);
    u32* bdata = (u32*)alloc((size_t)E * 4);
    f16* wf1h = (f16*)alloc(16384 * 2);
    f16* wf1l = (f16*)alloc(16384 * 2);
    f16* wf2h = (f16*)alloc(16384 * 2);
    f16* wf2l = (f16*)alloc(16384 * 2);
    f16* wf3h = (f16*)alloc(2048 * 2);
    f16* wf3l = (f16*)alloc(2048 * 2);
    f16* h = (f16*)alloc((size_t)(N + 1) * 128 * 2);   // +1 sentinel zero row
    f16* act = (f16*)alloc((size_t)N * 128 * 2);
    f16* h3 = (f16*)alloc((size_t)(N + 1) * 16 * 2);   // +1 sentinel zero row
    (void)ws_size; (void)n_in; (void)out_size;

    hipMemsetAsync(flag, 0, 4, stream);

    int nb2 = (L + 255) / 256;  // 300 <= 512 for scan2

    detect_k<<<32, 256, 0, stream>>>(ei, flag, 8192);
    hist_k<<<NB, 256, 0, stream>>>(ei, flag, Hmat, E, N, NBK, NB);
    scan1<<<nb2, 256, 0, stream>>>(Hmat, Hmat, partial2, L);
    scan2<<<1, 512, 0, stream>>>(partial2, nb2);
    scan3<<<nb2, 256, 0, stream>>>(Hmat, partial2, L, E);  // sentinel Hmat[L]=E
    scatter_bd<<<NB, 256, 0, stream>>>(ei, flag, Hmat, bdata, E, N, NBK, NB);
    finalize_k<<<NBK, 256, 0, stream>>>(bdata, Hmat, row_start, rend, dinv,
                                        ecol, N, E, NB);

    reformat_all<<<18, 256, 0, stream>>>(W1, W2, W3, wf1h, wf1l, wf2h, wf2l,
                                         wf3h, wf3l,
                                         h + (size_t)N * 128,
                                         h3 + (size_t)N * 16);

    int gb = (N + 63) / 64;
    int ab = (N + 3) / 4;
    gemm128_l1<<<gb, 256, 0, stream>>>(x, wf1h, wf1l, dinv, h, N);
    agg128<<<ab, 256, 0, stream>>>(h, ecol, row_start, rend, dinv, b1, act, N);
    gemm128_l2<<<gb, 256, 0, stream>>>(act, wf2h, wf2l, h, N);
    agg128<<<ab, 256, 0, stream>>>(h, ecol, row_start, rend, dinv, b2, act, N);
    gemm16<<<gb, 256, 0, stream>>>(act, wf3h, wf3l, h3, N);
    agg16_lsm<<<(N + 15) / 16, 256, 0, stream>>>(h3, ecol, row_start, rend,
                                                 dinv, b3, (float*)d_out, N);
}

// Round 2
// 381.041 us; speedup vs baseline: 1.0246x; 1.0059x over previous
//
#include <hip/hip_runtime.h>

typedef unsigned int u32;
typedef _Float16 f16;
typedef __attribute__((ext_vector_type(8))) _Float16 half8;
typedef __attribute__((ext_vector_type(2))) _Float16 half2_t;
typedef __attribute__((ext_vector_type(4))) float f32x4;

#define D_IN 128
#define D_HID 128
#define D_OUT 16
#define RPB 128        // rows per bucket (lr fits in 7 bits; c < 2^20)
#define MAXBUCK 1024   // supports N <= 131072
#define CHUNK 16384    // edges per hist/scatter block (256 thr x 64)
#define PGRAN 4        // pad each row's edge run to a multiple of 4
#define SLACK 2048     // per-bucket capacity bonus; mult of 16, >= 128*3+15
                       // (also provides >=16 valid-to-read u32 past last rend)

// ---------------- preprocessing ----------------

// flag: 1 if edge_index is int32 layout, 0 if int64 (odd words all zero).
__global__ __launch_bounds__(256) void detect_k(const int* __restrict__ ei,
                                                u32* __restrict__ flag, int n) {
    int i = blockIdx.x * 256 + threadIdx.x;
    if (i < n && (i & 1) && ei[i] != 0) atomicOr(flag, 1u);
}

__device__ inline int load_row(const int* ei, u32 f, int e, int E) {
    return f ? ei[e] : ei[2 * e];
}
__device__ inline int load_col(const int* ei, u32 f, int e, int E) {
    return f ? ei[E + e] : ei[2 * E + 2 * e];
}
__device__ inline int clampi(int v, int n) {
    v = v < 0 ? 0 : v;
    return v >= n ? n - 1 : v;
}
__device__ inline u32 al16(u32 v) { return (v + 15u) & ~15u; }

// Pass 1: per-block histogram over row-buckets (bucket-major Hmat, plain
// stores — no global atomics at all).
__global__ __launch_bounds__(256) void hist_k(const int* __restrict__ ei,
                                              const u32* __restrict__ flag,
                                              u32* __restrict__ Hmat,
                                              int E, int N, int NBK, int NB) {
    __shared__ u32 lh[MAXBUCK];
    int tid = threadIdx.x;
    for (int i = tid; i < NBK; i += 256) lh[i] = 0;
    __syncthreads();
    u32 f = *flag;
    int base = blockIdx.x * CHUNK;
    int lim = base + CHUNK < E ? base + CHUNK : E;
    for (int e = base + tid; e < lim; e += 256) {
        int r = clampi(load_row(ei, f, e, E), N);
        atomicAdd(&lh[(u32)r >> 7], 1u);
    }
    __syncthreads();
    for (int i = tid; i < NBK; i += 256)
        Hmat[(size_t)i * NB + blockIdx.x] = lh[i];
}

__global__ __launch_bounds__(256) void scan1(const u32* __restrict__ cnt,
                                             u32* __restrict__ excl,
                                             u32* __restrict__ partial, int n) {
    __shared__ u32 sm[256];
    int tid = threadIdx.x;
    int i = blockIdx.x * 256 + tid;
    u32 v = (i < n) ? cnt[i] : 0u;
    sm[tid] = v;
    __syncthreads();
    for (int off = 1; off < 256; off <<= 1) {
        u32 t = (tid >= off) ? sm[tid - off] : 0u;
        __syncthreads();
        sm[tid] += t;
        __syncthreads();
    }
    if (i < n) excl[i] = sm[tid] - v;
    if (tid == 255) partial[blockIdx.x] = sm[255];
}

__global__ __launch_bounds__(512) void scan2(u32* __restrict__ partial, int nb) {
    __shared__ u32 sm[512];
    int tid = threadIdx.x;
    u32 v = (tid < nb) ? partial[tid] : 0u;
    sm[tid] = v;
    __syncthreads();
    for (int off = 1; off < 512; off <<= 1) {
        u32 t = (tid >= off) ? sm[tid - off] : 0u;
        __syncthreads();
        sm[tid] += t;
        __syncthreads();
    }
    if (tid < nb) partial[tid] = sm[tid] - v;
}

__global__ __launch_bounds__(256) void scan3(u32* __restrict__ excl,
                                             const u32* __restrict__ partial,
                                             int n, int E) {
    int i = blockIdx.x * 256 + threadIdx.x;
    if (i < n) excl[i] += partial[blockIdx.x];
    if (i == 0) excl[n] = (u32)E;
}

// Pass 2: re-read edges; block-exact frontiers per bucket (from scanned Hmat),
// only LDS atomics. Record = (r&127)<<20 | c (u32, c < 2^20).
__global__ __launch_bounds__(256) void scatter_bd(const int* __restrict__ ei,
                                                  const u32* __restrict__ flag,
                                                  const u32* __restrict__ Hbase,
                                                  u32* __restrict__ bdata,
                                                  int E, int N, int NBK, int NB) {
    __shared__ u32 lbase[MAXBUCK];
    int tid = threadIdx.x;
    for (int i = tid; i < NBK; i += 256)
        lbase[i] = Hbase[(size_t)i * NB + blockIdx.x];
    __syncthreads();
    u32 f = *flag;
    int base = blockIdx.x * CHUNK;
    int lim = base + CHUNK < E ? base + CHUNK : E;
    for (int e = base + tid; e < lim; e += 256) {
        int r = clampi(load_row(ei, f, e, E), N);
        int c = clampi(load_col(ei, f, e, E), N);
        u32 pos = atomicAdd(&lbase[(u32)r >> 7], 1u);
        if (pos < (u32)E) bdata[pos] = ((u32)(r & (RPB - 1)) << 20) | (u32)c;
    }
}

// Pass 3: PADDED CSR with per-row (start,end) packed in ONE uint2 (R13: one
// s_load_dwordx2 instead of two dependent s_loads on the agg critical path).
// rend-beg = pdeg (mult of PGRAN, pad -> sentinel col N). Bucket slack is
// NEVER accumulated (masked to sentinel in agg), only read as garbage cols
// whose OFFSET is replaced before the gather.
__global__ __launch_bounds__(256) void finalize_k(const u32* __restrict__ bdata,
                                                  const u32* __restrict__ Hbase,
                                                  uint2* __restrict__ rdesc,
                                                  float* __restrict__ dinv,
                                                  u32* __restrict__ ecol,
                                                  int N, int E, int NB) {
    __shared__ u32 smc[RPB];
    __shared__ u32 cur[RPB];
    int b = blockIdx.x;
    int tid = threadIdx.x;
    u32 s = Hbase[(size_t)b * NB];
    u32 t = Hbase[(size_t)(b + 1) * NB];  // last bucket hits sentinel = E
    u32 pbase = al16(s) + (u32)b * SLACK;
    if (tid < RPB) smc[tid] = 0;
    __syncthreads();
    for (u32 i = s + tid; i < t; i += 256)
        atomicAdd(&smc[bdata[i] >> 20], 1u);
    __syncthreads();
    u32 deg = (tid < RPB) ? smc[tid] : 0;
    u32 pdeg = (deg + PGRAN - 1) & ~(u32)(PGRAN - 1);
    if (tid < RPB) smc[tid] = pdeg;
    __syncthreads();
    for (int off = 1; off < RPB; off <<= 1) {
        u32 tv = (tid < RPB && tid >= off) ? smc[tid - off] : 0u;
        __syncthreads();
        if (tid < RPB) smc[tid] += tv;
        __syncthreads();
    }
    u32 pexcl = (tid < RPB) ? (smc[tid] - pdeg) : 0;
    if (tid < RPB) {
        int r = b * RPB + tid;
        if (r < N) {
            rdesc[r] = make_uint2(pbase + pexcl, pbase + pexcl + pdeg);
            dinv[r] = rsqrtf((float)(deg + 1u));  // +1 self loop
        }
        cur[tid] = pbase + pexcl;
    }
    __syncthreads();
    for (u32 i = s + tid; i < t; i += 256) {
        u32 rec = bdata[i];
        u32 pos = atomicAdd(&cur[rec >> 20], 1u);
        ecol[pos] = rec & 0xFFFFFu;
    }
    __syncthreads();
    if (tid < RPB) {  // per-row pad tail -> sentinel zero-row
        u32 st = pbase + pexcl;
        for (u32 k = deg; k < pdeg; k++) ecol[st + k] = (u32)N;
    }
    // bucket slack never accumulated (agg masks offsets past rend) -> no fill.
}

// Split fp32 W into hi/lo f16 MFMA B-fragments. Blocks 0-7 -> W1, 8-15 -> W2,
// 16 -> W3, 17 -> zero the sentinel rows h[N], h3[N].
__global__ __launch_bounds__(256) void reformat_all(const float* __restrict__ W1,
                                                    const float* __restrict__ W2,
                                                    const float* __restrict__ W3,
                                                    f16* __restrict__ W1h, f16* __restrict__ W1l,
                                                    f16* __restrict__ W2h, f16* __restrict__ W2l,
                                                    f16* __restrict__ W3h, f16* __restrict__ W3l,
                                                    f16* __restrict__ hzero,
                                                    f16* __restrict__ h3zero) {
    if (blockIdx.x == 17) {
        int tix = threadIdx.x;
        if (tix < 128) hzero[tix] = (f16)0;
        else if (tix < 144) h3zero[tix - 128] = (f16)0;
        return;
    }
    const float* W;
    f16 *Wh, *Wl;
    int ntiles, bidx;
    if (blockIdx.x < 8) { W = W1; Wh = W1h; Wl = W1l; ntiles = 8; bidx = blockIdx.x; }
    else if (blockIdx.x < 16) { W = W2; Wh = W2h; Wl = W2l; ntiles = 8; bidx = blockIdx.x - 8; }
    else { W = W3; Wh = W3h; Wl = W3l; ntiles = 1; bidx = 0; }
    int idx = bidx * 256 + threadIdx.x;
    int total = 4 * ntiles * 64;
    if (idx >= total) return;
    int lane = idx & 63;
    int st = idx >> 6;
    int t = st % ntiles;
    int s = st / ntiles;
    int Nc = ntiles * 16;
    int n = t * 16 + (lane & 15);
    int kb = lane >> 4;
    half8 vh, vl;
#pragma unroll
    for (int j = 0; j < 8; j++) {
        float w = W[(size_t)(s * 32 + kb * 8 + j) * Nc + n];
        f16 hi = (f16)w;
        f16 lo = (f16)(w - (float)hi);
        vh[j] = hi;
        vl[j] = lo;
    }
    *(half8*)(Wh + (size_t)idx * 8) = vh;
    *(half8*)(Wl + (size_t)idx * 8) = vl;
}

// ---------------- GEMMs (f16 MFMA 16x16x32, fp32-accurate via splits) --------

// Layer 1: A fp32 [M x 128]; 3 MFMAs; epilogue scales row rr by dinv[rr]
// so the stored table is h' = (x@W1)*dinv  (norm folded into storage).
__global__ __launch_bounds__(256) void gemm128_l1(const float* __restrict__ A,
                                                  const f16* __restrict__ Wh,
                                                  const f16* __restrict__ Wl,
                                                  const float* __restrict__ dinv,
                                                  f16* __restrict__ H, int M) {
    int wave = threadIdx.x >> 6, lane = threadIdx.x & 63;
    int mbase = blockIdx.x * 64 + wave * 16;
    int mload = mbase + (lane & 15);
    if (mload >= M) mload = M - 1;
    int kq = lane >> 4;
    f32x4 acc[8];
#pragma unroll
    for (int t = 0; t < 8; t++) acc[t] = (f32x4){0.f, 0.f, 0.f, 0.f};
#pragma unroll
    for (int s = 0; s < 4; s++) {
        const float* ap = A + (size_t)mload * 128 + s * 32 + kq * 8;
        half8 ah, al;
#pragma unroll
        for (int j = 0; j < 8; j++) {
            float v = ap[j];
            f16 hi = (f16)v;
            ah[j] = hi;
            al[j] = (f16)(v - (float)hi);
        }
#pragma unroll
        for (int t = 0; t < 8; t++) {
            half8 bh = *(const half8*)(Wh + (size_t)((s * 8 + t) * 64 + lane) * 8);
            half8 bl = *(const half8*)(Wl + (size_t)((s * 8 + t) * 64 + lane) * 8);
            acc[t] = __builtin_amdgcn_mfma_f32_16x16x32_f16(ah, bh, acc[t], 0, 0, 0);
            acc[t] = __builtin_amdgcn_mfma_f32_16x16x32_f16(ah, bl, acc[t], 0, 0, 0);
            acc[t] = __builtin_amdgcn_mfma_f32_16x16x32_f16(al, bh, acc[t], 0, 0, 0);
        }
    }
    int coln = lane & 15;
    int rbase = mbase + ((lane >> 4) << 2);
    float dsc[4];
#pragma unroll
    for (int i = 0; i < 4; i++) {
        int rr = rbase + i;
        dsc[i] = dinv[rr < M ? rr : M - 1];
    }
#pragma unroll
    for (int t = 0; t < 8; t++) {
#pragma unroll
        for (int i = 0; i < 4; i++) {
            int rr = rbase + i;
            if (rr < M) H[(size_t)rr * 128 + t * 16 + coln] = (f16)(acc[t][i] * dsc[i]);
        }
    }
}

// Layer 2: A f16 (pre-scaled act') [M x 128]; 2 MFMAs; output inherits the
// dinv row-scale automatically ((act*dinv)@W = (act@W)*dinv).
__global__ __launch_bounds__(256) void gemm128_l2(const f16* __restrict__ A,
                                                  const f16* __restrict__ Wh,
                                                  const f16* __restrict__ Wl,
                                                  f16* __restrict__ H, int M) {
    int wave = threadIdx.x >> 6, lane = threadIdx.x & 63;
    int mbase = blockIdx.x * 64 + wave * 16;
    int mload = mbase + (lane & 15);
    if (mload >= M) mload = M - 1;
    int kq = lane >> 4;
    f32x4 acc[8];
#pragma unroll
    for (int t = 0; t < 8; t++) acc[t] = (f32x4){0.f, 0.f, 0.f, 0.f};
#pragma unroll
    for (int s = 0; s < 4; s++) {
        half8 a = *(const half8*)(A + (size_t)mload * 128 + s * 32 + kq * 8);
#pragma unroll
        for (int t = 0; t < 8; t++) {
            half8 bh = *(const half8*)(Wh + (size_t)((s * 8 + t) * 64 + lane) * 8);
            half8 bl = *(const half8*)(Wl + (size_t)((s * 8 + t) * 64 + lane) * 8);
            acc[t] = __builtin_amdgcn_mfma_f32_16x16x32_f16(a, bh, acc[t], 0, 0, 0);
            acc[t] = __builtin_amdgcn_mfma_f32_16x16x32_f16(a, bl, acc[t], 0, 0, 0);
        }
    }
    int coln = lane & 15;
    int rbase = mbase + ((lane >> 4) << 2);
#pragma unroll
    for (int t = 0; t < 8; t++) {
#pragma unroll
        for (int i = 0; i < 4; i++) {
            int rr = rbase + i;
            if (rr < M) H[(size_t)rr * 128 + t * 16 + coln] = (f16)acc[t][i];
        }
    }
}

// Layer 3: A f16 (pre-scaled) [M x 128] -> H3' f16 [M x 16].
__global__ __launch_bounds__(256) void gemm16(const f16* __restrict__ A,
                                              const f16* __restrict__ Wh,
                                              const f16* __restrict__ Wl,
                                              f16* __restrict__ H, int M) {
    int wave = threadIdx.x >> 6, lane = threadIdx.x & 63;
    int mbase = blockIdx.x * 64 + wave * 16;
    int mload = mbase + (lane & 15);
    if (mload >= M) mload = M - 1;
    int kq = lane >> 4;
    f32x4 acc = (f32x4){0.f, 0.f, 0.f, 0.f};
#pragma unroll
    for (int s = 0; s < 4; s++) {
        half8 a = *(const half8*)(A + (size_t)mload * 128 + s * 32 + kq * 8);
        half8 bh = *(const half8*)(Wh + (size_t)(s * 64 + lane) * 8);
        half8 bl = *(const half8*)(Wl + (size_t)(s * 64 + lane) * 8);
        acc = __builtin_amdgcn_mfma_f32_16x16x32_f16(a, bh, acc, 0, 0, 0);
        acc = __builtin_amdgcn_mfma_f32_16x16x32_f16(a, bl, acc, 0, 0, 0);
    }
    int coln = lane & 15;
    int rbase = mbase + ((lane >> 4) << 2);
#pragma unroll
    for (int i = 0; i < 4; i++) {
        int rr = rbase + i;
        if (rr < M) H[(size_t)rr * 16 + coln] = (f16)acc[i];
    }
}

// ---------------- aggregation ----------------
// R13: TWO rows per wave, software-pipelined. R12 analysis: fill volume is
// structural (each XCD streams the whole 25.6MB h table once = 195MB) but a
// 1-row wave has gathers in flight only ~40% of its lifetime (serial chain:
// s_load bounds -> s_load cols -> gathers -> vmcnt(0) -> epilogue loads).
// Fix: (a) issue row B's 16 gathers while accumulating row A and vice versa
// (~32 x 256B in flight); (b) hoist ALL epilogue loads (self row, bias, dinv)
// above the loop; (c) one uint2 descriptor load per row; (d) variable length
// handled by selecting the SENTINEL-ROW OFFSET for out-of-range slots before
// the gather (sentinel row is zeros + L1-hot -> accumulates 0 at no HBM cost;
// reading ecol up to 15 past rend stays inside the bucket slack).
__global__ __launch_bounds__(256) void agg128(const f16* __restrict__ h,
                                              const u32* __restrict__ ecol,
                                              const uint2* __restrict__ rdesc,
                                              const float* __restrict__ dinv,
                                              const float* __restrict__ bias,
                                              f16* __restrict__ out, int M) {
    int lane = threadIdx.x & 63;
    int wave = __builtin_amdgcn_readfirstlane(threadIdx.x >> 6);
    int r0 = (blockIdx.x * 4 + wave) * 2;
    if (r0 >= M) return;
    int r1 = (r0 + 1 < M) ? r0 + 1 : r0;  // dup row ok: same value written twice
    uint2 dA = rdesc[r0];
    uint2 dB = rdesc[r1];
    u32 eA = (u32)__builtin_amdgcn_readfirstlane((int)dA.x);
    u32 endA = (u32)__builtin_amdgcn_readfirstlane((int)dA.y);
    u32 eB = (u32)__builtin_amdgcn_readfirstlane((int)dB.x);
    u32 endB = (u32)__builtin_amdgcn_readfirstlane((int)dB.y);
    float drA = dinv[r0], drB = dinv[r1];
    const char* hb = (const char*)h;
    u32 loff = (u32)lane << 2;
    u32 sentoff = ((u32)M << 8) + loff;  // sentinel (zero) row
    // hoisted epilogue loads — overlap with the gather phase
    float2 bb = ((const float2*)bias)[lane];
    half2_t vsA = *(const half2_t*)(hb + (((u32)r0 << 8) + loff));
    half2_t vsB = *(const half2_t*)(hb + (((u32)r1 << 8) + loff));

#define GATHER16(vv, ebase, endv)                                         \
    {                                                                     \
        const u32* ep = ecol + (ebase);                                   \
        _Pragma("unroll") for (int j = 0; j < 16; j++) {                  \
            u32 off = (ep[j] << 8) + loff;                                \
            off = ((ebase) + (u32)j < (endv)) ? off : sentoff;            \
            vv[j] = *(const half2_t*)(hb + off);                          \
        }                                                                 \
    }

    float axA0 = 0, ayA0 = 0, axA1 = 0, ayA1 = 0, axA2 = 0, ayA2 = 0, axA3 = 0, ayA3 = 0;
    float axB0 = 0, ayB0 = 0, axB1 = 0, ayB1 = 0, axB2 = 0, ayB2 = 0, axB3 = 0, ayB3 = 0;
    half2_t vA[16], vB[16];
    GATHER16(vA, eA, endA);  // batch 0 for both rows in flight together
    GATHER16(vB, eB, endB);
    bool liveA = true, liveB = true;
    while (liveA || liveB) {
        if (liveA) {
#pragma unroll
            for (int j = 0; j < 16; j += 4) {
                axA0 = fmaf((float)vA[j][0],     drA, axA0); ayA0 = fmaf((float)vA[j][1],     drA, ayA0);
                axA1 = fmaf((float)vA[j + 1][0], drA, axA1); ayA1 = fmaf((float)vA[j + 1][1], drA, ayA1);
                axA2 = fmaf((float)vA[j + 2][0], drA, axA2); ayA2 = fmaf((float)vA[j + 2][1], drA, ayA2);
                axA3 = fmaf((float)vA[j + 3][0], drA, axA3); ayA3 = fmaf((float)vA[j + 3][1], drA, ayA3);
            }
            eA += 16;
            liveA = eA < endA;
            if (liveA) GATHER16(vA, eA, endA);  // overlaps row B's accumulate
        }
        if (liveB) {
#pragma unroll
            for (int j = 0; j < 16; j += 4) {
                axB0 = fmaf((float)vB[j][0],     drB, axB0); ayB0 = fmaf((float)vB[j][1],     drB, ayB0);
                axB1 = fmaf((float)vB[j + 1][0], drB, axB1); ayB1 = fmaf((float)vB[j + 1][1], drB, ayB1);
                axB2 = fmaf((float)vB[j + 2][0], drB, axB2); ayB2 = fmaf((float)vB[j + 2][1], drB, ayB2);
                axB3 = fmaf((float)vB[j + 3][0], drB, axB3); ayB3 = fmaf((float)vB[j + 3][1], drB, ayB3);
            }
            eB += 16;
            liveB = eB < endB;
            if (liveB) GATHER16(vB, eB, endB);
        }
    }
#undef GATHER16
    float ax = ((axA0 + axA1) + (axA2 + axA3)) + fmaf((float)vsA[0], drA, bb.x);
    float ay = ((ayA0 + ayA1) + (ayA2 + ayA3)) + fmaf((float)vsA[1], drA, bb.y);
    ax = fmaxf(ax, 0.f) * drA;  // pre-scale for next layer's gather
    ay = fmaxf(ay, 0.f) * drA;
    half2_t oA;
    oA[0] = (f16)ax;
    oA[1] = (f16)ay;
    ((half2_t*)out)[(size_t)r0 * 64 + lane] = oA;
    float bx = ((axB0 + axB1) + (axB2 + axB3)) + fmaf((float)vsB[0], drB, bb.x);
    float by = ((ayB0 + ayB1) + (ayB2 + ayB3)) + fmaf((float)vsB[1], drB, bb.y);
    bx = fmaxf(bx, 0.f) * drB;
    by = fmaxf(by, 0.f) * drB;
    half2_t oB;
    oB[0] = (f16)bx;
    oB[1] = (f16)by;
    ((half2_t*)out)[(size_t)r1 * 64 + lane] = oB;
}

// 16 lanes per row; h3' pre-scaled; padded CSR (PGRAN=4) -> 8-batches + one
// optional 4-batch tail; uint2 descriptor + hoisted self/bias loads.
__global__ __launch_bounds__(256) void agg16_lsm(const f16* __restrict__ h3,
                                                 const u32* __restrict__ ecol,
                                                 const uint2* __restrict__ rdesc,
                                                 const float* __restrict__ dinv,
                                                 const float* __restrict__ bias,
                                                 float* __restrict__ out, int M) {
    int g = threadIdx.x >> 4, l = threadIdx.x & 15;
    int r = blockIdx.x * 16 + g;
    if (r >= M) return;
    uint2 d = rdesc[r];
    u32 beg = d.x, end = d.y;
    float dr = dinv[r];
    float bl = bias[l];
    float self = (float)h3[(size_t)r * 16 + l];
    float a0 = 0.f, a1 = 0.f, a2 = 0.f, a3 = 0.f;
    u32 e = beg;
    for (; e + 8 <= end; e += 8) {
        u32 c[8];
#pragma unroll
        for (int j = 0; j < 8; j++) c[j] = ecol[e + j];
        f16 v[8];
#pragma unroll
        for (int j = 0; j < 8; j++) v[j] = h3[(size_t)c[j] * 16 + l];
        a0 += (float)v[0] + (float)v[4];
        a1 += (float)v[1] + (float)v[5];
        a2 += (float)v[2] + (float)v[6];
        a3 += (float)v[3] + (float)v[7];
    }
    if (e < end) {  // remainder is exactly 4
        u32 c[4];
#pragma unroll
        for (int j = 0; j < 4; j++) c[j] = ecol[e + j];
        f16 v[4];
#pragma unroll
        for (int j = 0; j < 4; j++) v[j] = h3[(size_t)c[j] * 16 + l];
        a0 += (float)v[0];
        a1 += (float)v[1];
        a2 += (float)v[2];
        a3 += (float)v[3];
    }
    float acc = (((a0 + a1) + (a2 + a3)) + self) * dr + bl;
    float m = acc;
#pragma unroll
    for (int o = 8; o >= 1; o >>= 1) m = fmaxf(m, __shfl_xor(m, o, 16));
    float ex = expf(acc - m);
    float s = ex;
#pragma unroll
    for (int o = 8; o >= 1; o >>= 1) s += __shfl_xor(s, o, 16);
    out[(size_t)r * 16 + l] = acc - m - logf(s);
}

// ---------------- launch ----------------

extern "C" void kernel_launch(void* const* d_in, const int* in_sizes, int n_in,
                              void* d_out, int out_size, void* d_ws, size_t ws_size,
                              hipStream_t stream) {
    const float* x = (const float*)d_in[0];
    const int* ei = (const int*)d_in[1];
    const float* W1 = (const float*)d_in[2];
    const float* b1 = (const float*)d_in[3];
    const float* W2 = (const float*)d_in[4];
    const float* b2 = (const float*)d_in[5];
    const float* W3 = (const float*)d_in[6];
    const float* b3 = (const float*)d_in[7];
    int N = in_sizes[0] / D_IN;
    int E = in_sizes[1] / 2;

    int NBK = (N + RPB - 1) / RPB;     // 782 row-buckets (<= MAXBUCK)
    int NB = (E + CHUNK - 1) / CHUNK;  // 98 hist/scatter blocks
    int L = NBK * NB;                  // 76636 Hmat entries
    size_t Epad = ((size_t)E + 16) + (size_t)NBK * SLACK + 256;

    char* p = (char*)d_ws;
    auto alloc = [&](size_t bytes) -> void* {
        void* q = (void*)p;
        p += (bytes + 255) & ~(size_t)255;
        return q;
    };
    u32* flag = (u32*)alloc(256);
    float* dinv = (float*)alloc((size_t)N * 4);
    uint2* rdesc = (uint2*)alloc((size_t)(N + 1) * 8);
    u32* partial2 = (u32*)alloc(4096);
    u32* Hmat = (u32*)alloc((size_t)(L + 1) * 4);
    u32* ecol = (u32*)alloc(Epad * 4);
    u32* bdata = (u32*)alloc((size_t)E * 4);
    f16* wf1h = (f16*)alloc(16384 * 2);
    f16* wf1l = (f16*)alloc(16384 * 2);
    f16* wf2h = (f16*)alloc(16384 * 2);
    f16* wf2l = (f16*)alloc(16384 * 2);
    f16* wf3h = (f16*)alloc(2048 * 2);
    f16* wf3l = (f16*)alloc(2048 * 2);
    f16* h = (f16*)alloc((size_t)(N + 1) * 128 * 2);   // +1 sentinel zero row
    f16* act = (f16*)alloc((size_t)N * 128 * 2);
    f16* h3 = (f16*)alloc((size_t)(N + 1) * 16 * 2);   // +1 sentinel zero row
    (void)ws_size; (void)n_in; (void)out_size;

    hipMemsetAsync(flag, 0, 4, stream);

    int nb2 = (L + 255) / 256;  // 300 <= 512 for scan2

    detect_k<<<32, 256, 0, stream>>>(ei, flag, 8192);
    hist_k<<<NB, 256, 0, stream>>>(ei, flag, Hmat, E, N, NBK, NB);
    scan1<<<nb2, 256, 0, stream>>>(Hmat, Hmat, partial2, L);
    scan2<<<1, 512, 0, stream>>>(partial2, nb2);
    scan3<<<nb2, 256, 0, stream>>>(Hmat, partial2, L, E);  // sentinel Hmat[L]=E
    scatter_bd<<<NB, 256, 0, stream>>>(ei, flag, Hmat, bdata, E, N, NBK, NB);
    finalize_k<<<NBK, 256, 0, stream>>>(bdata, Hmat, rdesc, dinv, ecol, N, E, NB);

    reformat_all<<<18, 256, 0, stream>>>(W1, W2, W3, wf1h, wf1l, wf2h, wf2l,
                                         wf3h, wf3l,
                                         h + (size_t)N * 128,
                                         h3 + (size_t)N * 16);

    int gb = (N + 63) / 64;
    int ab = (N + 7) / 8;  // 8 rows per block (2 per wave)
    gemm128_l1<<<gb, 256, 0, stream>>>(x, wf1h, wf1l, dinv, h, N);
    agg128<<<ab, 256, 0, stream>>>(h, ecol, rdesc, dinv, b1, act, N);
    gemm128_l2<<<gb, 256, 0, stream>>>(act, wf2h, wf2l, h, N);
    agg128<<<ab, 256, 0, stream>>>(h, ecol, rdesc, dinv, b2, act, N);
    gemm16<<<gb, 256, 0, stream>>>(act, wf3h, wf3l, h3, N);
    agg16_lsm<<<(N + 15) / 16, 256, 0, stream>>>(h3, ecol, rdesc,
                                                 dinv, b3, (float*)d_out, N);
}

// Round 3
// 336.176 us; speedup vs baseline: 1.1613x; 1.1335x over previous
//
#include <hip/hip_runtime.h>

typedef unsigned int u32;
typedef _Float16 f16;
typedef __attribute__((ext_vector_type(8))) _Float16 half8;
typedef __attribute__((ext_vector_type(2))) _Float16 half2_t;
typedef __attribute__((ext_vector_type(4))) float f32x4;

#define D_IN 128
#define D_HID 128
#define D_OUT 16
#define RPB 128        // rows per bucket (lr fits in 7 bits; c < 2^20)
#define MAXBUCK 1024   // supports N <= 131072
#define CHUNK 10240    // edges per hist/scatter block (R14: 16384 -> 10240,
                       // NB 98 -> 157 blocks = better CU coverage; nb2=480<=512)
#define PGRAN 4        // pad each row's edge run to a multiple of 4
#define SLACK 2048     // per-bucket capacity bonus; mult of 16, >= 128*3+15

// ---------------- preprocessing ----------------

// flag: 1 if edge_index is int32 layout, 0 if int64 (odd words all zero).
__global__ __launch_bounds__(256) void detect_k(const int* __restrict__ ei,
                                                u32* __restrict__ flag, int n) {
    int i = blockIdx.x * 256 + threadIdx.x;
    if (i < n && (i & 1) && ei[i] != 0) atomicOr(flag, 1u);
}

__device__ inline int load_row(const int* ei, u32 f, int e, int E) {
    return f ? ei[e] : ei[2 * e];
}
__device__ inline int load_col(const int* ei, u32 f, int e, int E) {
    return f ? ei[E + e] : ei[2 * E + 2 * e];
}
__device__ inline int clampi(int v, int n) {
    v = v < 0 ? 0 : v;
    return v >= n ? n - 1 : v;
}
__device__ inline u32 al16(u32 v) { return (v + 15u) & ~15u; }

// Pass 1: per-block histogram over row-buckets (bucket-major Hmat, plain
// stores — no global atomics). R14: 4-way unrolled loads so 4 strided int64
// reads are in flight before the LDS atomics (was 1 load -> 1 atomic serial).
__global__ __launch_bounds__(256) void hist_k(const int* __restrict__ ei,
                                              const u32* __restrict__ flag,
                                              u32* __restrict__ Hmat,
                                              int E, int N, int NBK, int NB) {
    __shared__ u32 lh[MAXBUCK];
    int tid = threadIdx.x;
    for (int i = tid; i < NBK; i += 256) lh[i] = 0;
    __syncthreads();
    u32 f = *flag;
    int base = blockIdx.x * CHUNK;
    int lim = base + CHUNK < E ? base + CHUNK : E;
    for (int e = base + tid; e < lim; e += 1024) {
        int e1 = e + 256, e2 = e + 512, e3 = e + 768;
        int r0 = clampi(load_row(ei, f, e, E), N);
        int r1 = (e1 < lim) ? clampi(load_row(ei, f, e1, E), N) : -1;
        int r2 = (e2 < lim) ? clampi(load_row(ei, f, e2, E), N) : -1;
        int r3 = (e3 < lim) ? clampi(load_row(ei, f, e3, E), N) : -1;
        atomicAdd(&lh[(u32)r0 >> 7], 1u);
        if (r1 >= 0) atomicAdd(&lh[(u32)r1 >> 7], 1u);
        if (r2 >= 0) atomicAdd(&lh[(u32)r2 >> 7], 1u);
        if (r3 >= 0) atomicAdd(&lh[(u32)r3 >> 7], 1u);
    }
    __syncthreads();
    for (int i = tid; i < NBK; i += 256)
        Hmat[(size_t)i * NB + blockIdx.x] = lh[i];
}

__global__ __launch_bounds__(256) void scan1(const u32* __restrict__ cnt,
                                             u32* __restrict__ excl,
                                             u32* __restrict__ partial, int n) {
    __shared__ u32 sm[256];
    int tid = threadIdx.x;
    int i = blockIdx.x * 256 + tid;
    u32 v = (i < n) ? cnt[i] : 0u;
    sm[tid] = v;
    __syncthreads();
    for (int off = 1; off < 256; off <<= 1) {
        u32 t = (tid >= off) ? sm[tid - off] : 0u;
        __syncthreads();
        sm[tid] += t;
        __syncthreads();
    }
    if (i < n) excl[i] = sm[tid] - v;
    if (tid == 255) partial[blockIdx.x] = sm[255];
}

__global__ __launch_bounds__(512) void scan2(u32* __restrict__ partial, int nb) {
    __shared__ u32 sm[512];
    int tid = threadIdx.x;
    u32 v = (tid < nb) ? partial[tid] : 0u;
    sm[tid] = v;
    __syncthreads();
    for (int off = 1; off < 512; off <<= 1) {
        u32 t = (tid >= off) ? sm[tid - off] : 0u;
        __syncthreads();
        sm[tid] += t;
        __syncthreads();
    }
    if (tid < nb) partial[tid] = sm[tid] - v;
}

__global__ __launch_bounds__(256) void scan3(u32* __restrict__ excl,
                                             const u32* __restrict__ partial,
                                             int n, int E) {
    int i = blockIdx.x * 256 + threadIdx.x;
    if (i < n) excl[i] += partial[blockIdx.x];
    if (i == 0) excl[n] = (u32)E;
}

// Pass 2: re-read edges; block-exact frontiers per bucket (from scanned Hmat),
// only LDS atomics. Record = (r&127)<<20 | c (u32, c < 2^20). 4-way unrolled.
__global__ __launch_bounds__(256) void scatter_bd(const int* __restrict__ ei,
                                                  const u32* __restrict__ flag,
                                                  const u32* __restrict__ Hbase,
                                                  u32* __restrict__ bdata,
                                                  int E, int N, int NBK, int NB) {
    __shared__ u32 lbase[MAXBUCK];
    int tid = threadIdx.x;
    for (int i = tid; i < NBK; i += 256)
        lbase[i] = Hbase[(size_t)i * NB + blockIdx.x];
    __syncthreads();
    u32 f = *flag;
    int base = blockIdx.x * CHUNK;
    int lim = base + CHUNK < E ? base + CHUNK : E;
    for (int e = base + tid; e < lim; e += 1024) {
        int e1 = e + 256, e2 = e + 512, e3 = e + 768;
        int r0 = clampi(load_row(ei, f, e, E), N);
        int c0 = clampi(load_col(ei, f, e, E), N);
        int r1 = -1, c1 = 0, r2 = -1, c2 = 0, r3 = -1, c3 = 0;
        if (e1 < lim) { r1 = clampi(load_row(ei, f, e1, E), N); c1 = clampi(load_col(ei, f, e1, E), N); }
        if (e2 < lim) { r2 = clampi(load_row(ei, f, e2, E), N); c2 = clampi(load_col(ei, f, e2, E), N); }
        if (e3 < lim) { r3 = clampi(load_row(ei, f, e3, E), N); c3 = clampi(load_col(ei, f, e3, E), N); }
        u32 pos = atomicAdd(&lbase[(u32)r0 >> 7], 1u);
        if (pos < (u32)E) bdata[pos] = ((u32)(r0 & (RPB - 1)) << 20) | (u32)c0;
        if (r1 >= 0) {
            pos = atomicAdd(&lbase[(u32)r1 >> 7], 1u);
            if (pos < (u32)E) bdata[pos] = ((u32)(r1 & (RPB - 1)) << 20) | (u32)c1;
        }
        if (r2 >= 0) {
            pos = atomicAdd(&lbase[(u32)r2 >> 7], 1u);
            if (pos < (u32)E) bdata[pos] = ((u32)(r2 & (RPB - 1)) << 20) | (u32)c2;
        }
        if (r3 >= 0) {
            pos = atomicAdd(&lbase[(u32)r3 >> 7], 1u);
            if (pos < (u32)E) bdata[pos] = ((u32)(r3 & (RPB - 1)) << 20) | (u32)c3;
        }
    }
}

// Pass 3: PADDED CSR with per-row (start,end) packed in ONE uint2.
// rend-beg = pdeg (mult of PGRAN, pad -> sentinel col N).
__global__ __launch_bounds__(256) void finalize_k(const u32* __restrict__ bdata,
                                                  const u32* __restrict__ Hbase,
                                                  uint2* __restrict__ rdesc,
                                                  float* __restrict__ dinv,
                                                  u32* __restrict__ ecol,
                                                  int N, int E, int NB) {
    __shared__ u32 smc[RPB];
    __shared__ u32 cur[RPB];
    int b = blockIdx.x;
    int tid = threadIdx.x;
    u32 s = Hbase[(size_t)b * NB];
    u32 t = Hbase[(size_t)(b + 1) * NB];  // last bucket hits sentinel = E
    u32 pbase = al16(s) + (u32)b * SLACK;
    if (tid < RPB) smc[tid] = 0;
    __syncthreads();
    for (u32 i = s + tid; i < t; i += 256)
        atomicAdd(&smc[bdata[i] >> 20], 1u);
    __syncthreads();
    u32 deg = (tid < RPB) ? smc[tid] : 0;
    u32 pdeg = (deg + PGRAN - 1) & ~(u32)(PGRAN - 1);
    if (tid < RPB) smc[tid] = pdeg;
    __syncthreads();
    for (int off = 1; off < RPB; off <<= 1) {
        u32 tv = (tid < RPB && tid >= off) ? smc[tid - off] : 0u;
        __syncthreads();
        if (tid < RPB) smc[tid] += tv;
        __syncthreads();
    }
    u32 pexcl = (tid < RPB) ? (smc[tid] - pdeg) : 0;
    if (tid < RPB) {
        int r = b * RPB + tid;
        if (r < N) {
            rdesc[r] = make_uint2(pbase + pexcl, pbase + pexcl + pdeg);
            dinv[r] = rsqrtf((float)(deg + 1u));  // +1 self loop
        }
        cur[tid] = pbase + pexcl;
    }
    __syncthreads();
    for (u32 i = s + tid; i < t; i += 256) {
        u32 rec = bdata[i];
        u32 pos = atomicAdd(&cur[rec >> 20], 1u);
        ecol[pos] = rec & 0xFFFFFu;
    }
    __syncthreads();
    if (tid < RPB) {  // per-row pad tail -> sentinel zero-row
        u32 st = pbase + pexcl;
        for (u32 k = deg; k < pdeg; k++) ecol[st + k] = (u32)N;
    }
}

// Split fp32 W into hi/lo f16 MFMA B-fragments. Blocks 0-7 -> W1, 8-15 -> W2,
// 16 -> W3, 17 -> zero the sentinel rows h[N], h3[N].
__global__ __launch_bounds__(256) void reformat_all(const float* __restrict__ W1,
                                                    const float* __restrict__ W2,
                                                    const float* __restrict__ W3,
                                                    f16* __restrict__ W1h, f16* __restrict__ W1l,
                                                    f16* __restrict__ W2h, f16* __restrict__ W2l,
                                                    f16* __restrict__ W3h, f16* __restrict__ W3l,
                                                    f16* __restrict__ hzero,
                                                    f16* __restrict__ h3zero) {
    if (blockIdx.x == 17) {
        int tix = threadIdx.x;
        if (tix < 128) hzero[tix] = (f16)0;
        else if (tix < 144) h3zero[tix - 128] = (f16)0;
        return;
    }
    const float* W;
    f16 *Wh, *Wl;
    int ntiles, bidx;
    if (blockIdx.x < 8) { W = W1; Wh = W1h; Wl = W1l; ntiles = 8; bidx = blockIdx.x; }
    else if (blockIdx.x < 16) { W = W2; Wh = W2h; Wl = W2l; ntiles = 8; bidx = blockIdx.x - 8; }
    else { W = W3; Wh = W3h; Wl = W3l; ntiles = 1; bidx = 0; }
    int idx = bidx * 256 + threadIdx.x;
    int total = 4 * ntiles * 64;
    if (idx >= total) return;
    int lane = idx & 63;
    int st = idx >> 6;
    int t = st % ntiles;
    int s = st / ntiles;
    int Nc = ntiles * 16;
    int n = t * 16 + (lane & 15);
    int kb = lane >> 4;
    half8 vh, vl;
#pragma unroll
    for (int j = 0; j < 8; j++) {
        float w = W[(size_t)(s * 32 + kb * 8 + j) * Nc + n];
        f16 hi = (f16)w;
        f16 lo = (f16)(w - (float)hi);
        vh[j] = hi;
        vl[j] = lo;
    }
    *(half8*)(Wh + (size_t)idx * 8) = vh;
    *(half8*)(Wl + (size_t)idx * 8) = vl;
}

// ---------------- GEMMs (f16 MFMA 16x16x32, fp32-accurate via splits) --------
// R14: Wh/Wl fragment tables staged in LDS once per block (was: every wave
// re-read all 64KB from L2 per tile loop -> 400-600MB L2 traffic per GEMM +
// exposed latency). A-fragments prefetched before the MFMA loop.

// Layer 1: A fp32 [M x 128]; 3 MFMAs; epilogue scales row rr by dinv[rr].
__global__ __launch_bounds__(256) void gemm128_l1(const float* __restrict__ A,
                                                  const f16* __restrict__ Wh,
                                                  const f16* __restrict__ Wl,
                                                  const float* __restrict__ dinv,
                                                  f16* __restrict__ H, int M) {
    __shared__ f16 sBh[2048 * 8];  // 32KB
    __shared__ f16 sBl[2048 * 8];  // 32KB
    for (int i = threadIdx.x; i < 2048; i += 256) {
        *(half8*)(sBh + (size_t)i * 8) = *(const half8*)(Wh + (size_t)i * 8);
        *(half8*)(sBl + (size_t)i * 8) = *(const half8*)(Wl + (size_t)i * 8);
    }
    int wave = threadIdx.x >> 6, lane = threadIdx.x & 63;
    int mbase = blockIdx.x * 64 + wave * 16;
    int mload = mbase + (lane & 15);
    if (mload >= M) mload = M - 1;
    int kq = lane >> 4;
    // prefetch all A fragments (fp32, 8 floats per s)
    f32x4 a0[4], a1[4];
#pragma unroll
    for (int s = 0; s < 4; s++) {
        const float* ap = A + (size_t)mload * 128 + s * 32 + kq * 8;
        a0[s] = *(const f32x4*)ap;
        a1[s] = *(const f32x4*)(ap + 4);
    }
    f32x4 acc[8];
#pragma unroll
    for (int t = 0; t < 8; t++) acc[t] = (f32x4){0.f, 0.f, 0.f, 0.f};
    __syncthreads();
#pragma unroll
    for (int s = 0; s < 4; s++) {
        half8 ah, al;
#pragma unroll
        for (int j = 0; j < 4; j++) {
            float v = a0[s][j];
            f16 hi = (f16)v;
            ah[j] = hi;
            al[j] = (f16)(v - (float)hi);
            float w = a1[s][j];
            f16 wi = (f16)w;
            ah[j + 4] = wi;
            al[j + 4] = (f16)(w - (float)wi);
        }
#pragma unroll
        for (int t = 0; t < 8; t++) {
            half8 bh = *(const half8*)(sBh + (size_t)((s * 8 + t) * 64 + lane) * 8);
            half8 bl = *(const half8*)(sBl + (size_t)((s * 8 + t) * 64 + lane) * 8);
            acc[t] = __builtin_amdgcn_mfma_f32_16x16x32_f16(ah, bh, acc[t], 0, 0, 0);
            acc[t] = __builtin_amdgcn_mfma_f32_16x16x32_f16(ah, bl, acc[t], 0, 0, 0);
            acc[t] = __builtin_amdgcn_mfma_f32_16x16x32_f16(al, bh, acc[t], 0, 0, 0);
        }
    }
    int coln = lane & 15;
    int rbase = mbase + ((lane >> 4) << 2);
    float dsc[4];
#pragma unroll
    for (int i = 0; i < 4; i++) {
        int rr = rbase + i;
        dsc[i] = dinv[rr < M ? rr : M - 1];
    }
#pragma unroll
    for (int t = 0; t < 8; t++) {
#pragma unroll
        for (int i = 0; i < 4; i++) {
            int rr = rbase + i;
            if (rr < M) H[(size_t)rr * 128 + t * 16 + coln] = (f16)(acc[t][i] * dsc[i]);
        }
    }
}

// Layer 2: A f16 (pre-scaled act') [M x 128]; 2 MFMAs.
__global__ __launch_bounds__(256) void gemm128_l2(const f16* __restrict__ A,
                                                  const f16* __restrict__ Wh,
                                                  const f16* __restrict__ Wl,
                                                  f16* __restrict__ H, int M) {
    __shared__ f16 sBh[2048 * 8];
    __shared__ f16 sBl[2048 * 8];
    for (int i = threadIdx.x; i < 2048; i += 256) {
        *(half8*)(sBh + (size_t)i * 8) = *(const half8*)(Wh + (size_t)i * 8);
        *(half8*)(sBl + (size_t)i * 8) = *(const half8*)(Wl + (size_t)i * 8);
    }
    int wave = threadIdx.x >> 6, lane = threadIdx.x & 63;
    int mbase = blockIdx.x * 64 + wave * 16;
    int mload = mbase + (lane & 15);
    if (mload >= M) mload = M - 1;
    int kq = lane >> 4;
    half8 a[4];
#pragma unroll
    for (int s = 0; s < 4; s++)
        a[s] = *(const half8*)(A + (size_t)mload * 128 + s * 32 + kq * 8);
    f32x4 acc[8];
#pragma unroll
    for (int t = 0; t < 8; t++) acc[t] = (f32x4){0.f, 0.f, 0.f, 0.f};
    __syncthreads();
#pragma unroll
    for (int s = 0; s < 4; s++) {
#pragma unroll
        for (int t = 0; t < 8; t++) {
            half8 bh = *(const half8*)(sBh + (size_t)((s * 8 + t) * 64 + lane) * 8);
            half8 bl = *(const half8*)(sBl + (size_t)((s * 8 + t) * 64 + lane) * 8);
            acc[t] = __builtin_amdgcn_mfma_f32_16x16x32_f16(a[s], bh, acc[t], 0, 0, 0);
            acc[t] = __builtin_amdgcn_mfma_f32_16x16x32_f16(a[s], bl, acc[t], 0, 0, 0);
        }
    }
    int coln = lane & 15;
    int rbase = mbase + ((lane >> 4) << 2);
#pragma unroll
    for (int t = 0; t < 8; t++) {
#pragma unroll
        for (int i = 0; i < 4; i++) {
            int rr = rbase + i;
            if (rr < M) H[(size_t)rr * 128 + t * 16 + coln] = (f16)acc[t][i];
        }
    }
}

// Layer 3: A f16 (pre-scaled) [M x 128] -> H3' f16 [M x 16].
__global__ __launch_bounds__(256) void gemm16(const f16* __restrict__ A,
                                              const f16* __restrict__ Wh,
                                              const f16* __restrict__ Wl,
                                              f16* __restrict__ H, int M) {
    __shared__ f16 sBh[256 * 8];  // 4KB
    __shared__ f16 sBl[256 * 8];  // 4KB
    if (threadIdx.x < 256) {
        int i = threadIdx.x;
        *(half8*)(sBh + (size_t)i * 8) = *(const half8*)(Wh + (size_t)i * 8);
        *(half8*)(sBl + (size_t)i * 8) = *(const half8*)(Wl + (size_t)i * 8);
    }
    int wave = threadIdx.x >> 6, lane = threadIdx.x & 63;
    int mbase = blockIdx.x * 64 + wave * 16;
    int mload = mbase + (lane & 15);
    if (mload >= M) mload = M - 1;
    int kq = lane >> 4;
    half8 a[4];
#pragma unroll
    for (int s = 0; s < 4; s++)
        a[s] = *(const half8*)(A + (size_t)mload * 128 + s * 32 + kq * 8);
    f32x4 acc = (f32x4){0.f, 0.f, 0.f, 0.f};
    __syncthreads();
#pragma unroll
    for (int s = 0; s < 4; s++) {
        half8 bh = *(const half8*)(sBh + (size_t)(s * 64 + lane) * 8);
        half8 bl = *(const half8*)(sBl + (size_t)(s * 64 + lane) * 8);
        acc = __builtin_amdgcn_mfma_f32_16x16x32_f16(a[s], bh, acc, 0, 0, 0);
        acc = __builtin_amdgcn_mfma_f32_16x16x32_f16(a[s], bl, acc, 0, 0, 0);
    }
    int coln = lane & 15;
    int rbase = mbase + ((lane >> 4) << 2);
#pragma unroll
    for (int i = 0; i < 4; i++) {
        int rr = rbase + i;
        if (rr < M) H[(size_t)rr * 16 + coln] = (f16)acc[i];
    }
}

// ---------------- aggregation ----------------
// R14: back to the R1 schedule (1 row/wave — 2-row pipeline was net-neutral:
// occupancy 73->42% cancelled the ILP gain and mask VALU doubled VALUBusy).
// Kept from R13: uint2 descriptor (one s_load) + hoisted self/bias loads.
__global__ __launch_bounds__(256) void agg128(const f16* __restrict__ h,
                                              const u32* __restrict__ ecol,
                                              const uint2* __restrict__ rdesc,
                                              const float* __restrict__ dinv,
                                              const float* __restrict__ bias,
                                              f16* __restrict__ out, int M) {
    int lane = threadIdx.x & 63;
    int wave = __builtin_amdgcn_readfirstlane(threadIdx.x >> 6);
    int r = blockIdx.x * 4 + wave;
    if (r >= M) return;
    uint2 d = rdesc[r];
    u32 e = (u32)__builtin_amdgcn_readfirstlane((int)d.x);
    u32 end = (u32)__builtin_amdgcn_readfirstlane((int)d.y);
    float dr = dinv[r];
    const char* hb = (const char*)h;
    u32 loff = (u32)lane << 2;
    // hoisted epilogue loads — overlap with the gather phase
    float2 bb = ((const float2*)bias)[lane];
    half2_t vs = *(const half2_t*)(hb + (((u32)r << 8) + loff));
    float ax0 = 0, ay0 = 0, ax1 = 0, ay1 = 0, ax2 = 0, ay2 = 0, ax3 = 0, ay3 = 0;
    for (; e + 16 <= end; e += 16) {
        const u32* ep = ecol + e;
        u32 c[16];
#pragma unroll
        for (int j = 0; j < 16; j++) c[j] = ep[j];
        half2_t v[16];
#pragma unroll
        for (int j = 0; j < 16; j++)
            v[j] = *(const half2_t*)(hb + ((c[j] << 8) + loff));
#pragma unroll
        for (int j = 0; j < 16; j += 4) {
            ax0 = fmaf((float)v[j][0],     dr, ax0); ay0 = fmaf((float)v[j][1],     dr, ay0);
            ax1 = fmaf((float)v[j + 1][0], dr, ax1); ay1 = fmaf((float)v[j + 1][1], dr, ay1);
            ax2 = fmaf((float)v[j + 2][0], dr, ax2); ay2 = fmaf((float)v[j + 2][1], dr, ay2);
            ax3 = fmaf((float)v[j + 3][0], dr, ax3); ay3 = fmaf((float)v[j + 3][1], dr, ay3);
        }
    }
    for (; e < end; e += 4) {  // tail: 0-3 iterations of 4 (pdeg mult of 4)
        const u32* ep = ecol + e;
        u32 c0 = ep[0], c1 = ep[1], c2 = ep[2], c3 = ep[3];
        half2_t v0 = *(const half2_t*)(hb + ((c0 << 8) + loff));
        half2_t v1 = *(const half2_t*)(hb + ((c1 << 8) + loff));
        half2_t v2 = *(const half2_t*)(hb + ((c2 << 8) + loff));
        half2_t v3 = *(const half2_t*)(hb + ((c3 << 8) + loff));
        ax0 = fmaf((float)v0[0], dr, ax0); ay0 = fmaf((float)v0[1], dr, ay0);
        ax1 = fmaf((float)v1[0], dr, ax1); ay1 = fmaf((float)v1[1], dr, ay1);
        ax2 = fmaf((float)v2[0], dr, ax2); ay2 = fmaf((float)v2[1], dr, ay2);
        ax3 = fmaf((float)v3[0], dr, ax3); ay3 = fmaf((float)v3[1], dr, ay3);
    }
    float ax = ((ax0 + ax1) + (ax2 + ax3)) + fmaf((float)vs[0], dr, bb.x);
    float ay = ((ay0 + ay1) + (ay2 + ay3)) + fmaf((float)vs[1], dr, bb.y);
    ax = fmaxf(ax, 0.f) * dr;  // pre-scale for next layer's gather
    ay = fmaxf(ay, 0.f) * dr;
    half2_t o;
    o[0] = (f16)ax;
    o[1] = (f16)ay;
    ((half2_t*)out)[(size_t)r * 64 + lane] = o;
}

// 16 lanes per row; h3' pre-scaled; padded CSR (PGRAN=4) -> 8-batches + one
// optional 4-batch tail; uint2 descriptor + hoisted self/bias loads.
__global__ __launch_bounds__(256) void agg16_lsm(const f16* __restrict__ h3,
                                                 const u32* __restrict__ ecol,
                                                 const uint2* __restrict__ rdesc,
                                                 const float* __restrict__ dinv,
                                                 const float* __restrict__ bias,
                                                 float* __restrict__ out, int M) {
    int g = threadIdx.x >> 4, l = threadIdx.x & 15;
    int r = blockIdx.x * 16 + g;
    if (r >= M) return;
    uint2 d = rdesc[r];
    u32 beg = d.x, end = d.y;
    float dr = dinv[r];
    float bl = bias[l];
    float self = (float)h3[(size_t)r * 16 + l];
    float a0 = 0.f, a1 = 0.f, a2 = 0.f, a3 = 0.f;
    u32 e = beg;
    for (; e + 8 <= end; e += 8) {
        u32 c[8];
#pragma unroll
        for (int j = 0; j < 8; j++) c[j] = ecol[e + j];
        f16 v[8];
#pragma unroll
        for (int j = 0; j < 8; j++) v[j] = h3[(size_t)c[j] * 16 + l];
        a0 += (float)v[0] + (float)v[4];
        a1 += (float)v[1] + (float)v[5];
        a2 += (float)v[2] + (float)v[6];
        a3 += (float)v[3] + (float)v[7];
    }
    if (e < end) {  // remainder is exactly 4
        u32 c[4];
#pragma unroll
        for (int j = 0; j < 4; j++) c[j] = ecol[e + j];
        f16 v[4];
#pragma unroll
        for (int j = 0; j < 4; j++) v[j] = h3[(size_t)c[j] * 16 + l];
        a0 += (float)v[0];
        a1 += (float)v[1];
        a2 += (float)v[2];
        a3 += (float)v[3];
    }
    float acc = (((a0 + a1) + (a2 + a3)) + self) * dr + bl;
    float m = acc;
#pragma unroll
    for (int o = 8; o >= 1; o >>= 1) m = fmaxf(m, __shfl_xor(m, o, 16));
    float ex = expf(acc - m);
    float s = ex;
#pragma unroll
    for (int o = 8; o >= 1; o >>= 1) s += __shfl_xor(s, o, 16);
    out[(size_t)r * 16 + l] = acc - m - logf(s);
}

// ---------------- launch ----------------

extern "C" void kernel_launch(void* const* d_in, const int* in_sizes, int n_in,
                              void* d_out, int out_size, void* d_ws, size_t ws_size,
                              hipStream_t stream) {
    const float* x = (const float*)d_in[0];
    const int* ei = (const int*)d_in[1];
    const float* W1 = (const float*)d_in[2];
    const float* b1 = (const float*)d_in[3];
    const float* W2 = (const float*)d_in[4];
    const float* b2 = (const float*)d_in[5];
    const float* W3 = (const float*)d_in[6];
    const float* b3 = (const float*)d_in[7];
    int N = in_sizes[0] / D_IN;
    int E = in_sizes[1] / 2;

    int NBK = (N + RPB - 1) / RPB;     // 782 row-buckets (<= MAXBUCK)
    int NB = (E + CHUNK - 1) / CHUNK;  // 157 hist/scatter blocks
    int L = NBK * NB;                  // ~122774 Hmat entries
    size_t Epad = ((size_t)E + 16) + (size_t)NBK * SLACK + 256;

    char* p = (char*)d_ws;
    auto alloc = [&](size_t bytes) -> void* {
        void* q = (void*)p;
        p += (bytes + 255) & ~(size_t)255;
        return q;
    };
    u32* flag = (u32*)alloc(256);
    float* dinv = (float*)alloc((size_t)N * 4);
    uint2* rdesc = (uint2*)alloc((size_t)(N + 1) * 8);
    u32* partial2 = (u32*)alloc(4096);
    u32* Hmat = (u32*)alloc((size_t)(L + 1) * 4);
    u32* ecol = (u32*)alloc(Epad * 4);
    u32* bdata = (u32*)alloc((size_t)E * 4);
    f16* wf1h = (f16*)alloc(16384 * 2);
    f16* wf1l = (f16*)alloc(16384 * 2);
    f16* wf2h = (f16*)alloc(16384 * 2);
    f16* wf2l = (f16*)alloc(16384 * 2);
    f16* wf3h = (f16*)alloc(2048 * 2);
    f16* wf3l = (f16*)alloc(2048 * 2);
    f16* h = (f16*)alloc((size_t)(N + 1) * 128 * 2);   // +1 sentinel zero row
    f16* act = (f16*)alloc((size_t)N * 128 * 2);
    f16* h3 = (f16*)alloc((size_t)(N + 1) * 16 * 2);   // +1 sentinel zero row
    (void)ws_size; (void)n_in; (void)out_size;

    hipMemsetAsync(flag, 0, 4, stream);

    int nb2 = (L + 255) / 256;  // 480 <= 512 for scan2

    detect_k<<<32, 256, 0, stream>>>(ei, flag, 8192);
    hist_k<<<NB, 256, 0, stream>>>(ei, flag, Hmat, E, N, NBK, NB);
    scan1<<<nb2, 256, 0, stream>>>(Hmat, Hmat, partial2, L);
    scan2<<<1, 512, 0, stream>>>(partial2, nb2);
    scan3<<<nb2, 256, 0, stream>>>(Hmat, partial2, L, E);  // sentinel Hmat[L]=E
    scatter_bd<<<NB, 256, 0, stream>>>(ei, flag, Hmat, bdata, E, N, NBK, NB);
    finalize_k<<<NBK, 256, 0, stream>>>(bdata, Hmat, rdesc, dinv, ecol, N, E, NB);

    reformat_all<<<18, 256, 0, stream>>>(W1, W2, W3, wf1h, wf1l, wf2h, wf2l,
                                         wf3h, wf3l,
                                         h + (size_t)N * 128,
                                         h3 + (size_t)N * 16);

    int gb = (N + 63) / 64;
    int ab = (N + 3) / 4;
    gemm128_l1<<<gb, 256, 0, stream>>>(x, wf1h, wf1l, dinv, h, N);
    agg128<<<ab, 256, 0, stream>>>(h, ecol, rdesc, dinv, b1, act, N);
    gemm128_l2<<<gb, 256, 0, stream>>>(act, wf2h, wf2l, h, N);
    agg128<<<ab, 256, 0, stream>>>(h, ecol, rdesc, dinv, b2, act, N);
    gemm16<<<gb, 256, 0, stream>>>(act, wf3h, wf3l, h3, N);
    agg16_lsm<<<(N + 15) / 16, 256, 0, stream>>>(h3, ecol, rdesc,
                                                 dinv, b3, (float*)d_out, N);
}

// Round 4
// 334.289 us; speedup vs baseline: 1.1678x; 1.0056x over previous
//
#include <hip/hip_runtime.h>

typedef unsigned int u32;
typedef _Float16 f16;
typedef __attribute__((ext_vector_type(8))) _Float16 half8;
typedef __attribute__((ext_vector_type(2))) _Float16 half2_t;
typedef __attribute__((ext_vector_type(4))) float f32x4;

#define D_IN 128
#define D_HID 128
#define D_OUT 16
#define RPB 128        // rows per bucket (lr fits in 7 bits; c < 2^20)
#define MAXBUCK 1024   // supports N <= 131072
#define CHUNK 10240    // edges per scatter block (157 blocks at E=1.6M)
#define PGRAN 4        // pad each row's edge run to a multiple of 4
#define CAP 3072       // bdata capacity per bucket (mean 2046, +22 sigma;
                       // R15: fixed regions kill the hist+scan subchain)
#define PCAP 3584      // ecol capacity per bucket; CAP + 512 >= CAP + 3*128 pad

// ---------------- preprocessing ----------------

__device__ inline int load_row(const int* ei, u32 f, int e, int E) {
    return f ? ei[e] : ei[2 * e];
}
__device__ inline int load_col(const int* ei, u32 f, int e, int E) {
    return f ? ei[E + e] : ei[2 * E + 2 * e];
}
__device__ inline int clampi(int v, int n) {
    v = v < 0 ? 0 : v;
    return v >= n ? n - 1 : v;
}

// R15 single scatter pass (replaces detect_k + hist_k + scan1/2/3 + scatter_bd):
//  - per-block layout detect on the first 8192 words (L2-hot after block 0)
//  - pass A: LDS histogram of this chunk's rows per bucket
//  - reserve: ONE global atomicAdd per (bucket,block) -> within-bucket base
//    (157 adds/address, vs 2046/address if per-edge -> no contention wall)
//  - pass B: re-read chunk (L2-hot), scatter records via LDS cursors into the
//    bucket's FIXED region [b*CAP, b*CAP+CAP). Record = (r&127)<<20 | c.
__global__ __launch_bounds__(256) void scatter_k(const int* __restrict__ ei,
                                                 u32* __restrict__ bcnt,
                                                 u32* __restrict__ bdata,
                                                 int E, int N, int NBK) {
    __shared__ u32 lcnt[MAXBUCK];
    __shared__ u32 lflag;
    int tid = threadIdx.x;
    if (tid == 0) lflag = 0;
    for (int i = tid; i < NBK; i += 256) lcnt[i] = 0;
    __syncthreads();
    // layout detect: any nonzero odd 32-bit word => int32 layout (int64 high
    // halves are all zero since 0 <= idx < 2^20).
    int nw = (2 * E < 8192) ? 2 * E : 8192;
    for (int k = tid * 2 + 1; k < nw; k += 512)
        if (ei[k] != 0) atomicOr(&lflag, 1u);
    __syncthreads();
    u32 f = lflag;
    int base = blockIdx.x * CHUNK;
    int lim = base + CHUNK < E ? base + CHUNK : E;
    // pass A: count (4-way unrolled so 4 strided loads are in flight)
    for (int e = base + tid; e < lim; e += 1024) {
        int e1 = e + 256, e2 = e + 512, e3 = e + 768;
        int r0 = clampi(load_row(ei, f, e, E), N);
        int r1 = (e1 < lim) ? clampi(load_row(ei, f, e1, E), N) : -1;
        int r2 = (e2 < lim) ? clampi(load_row(ei, f, e2, E), N) : -1;
        int r3 = (e3 < lim) ? clampi(load_row(ei, f, e3, E), N) : -1;
        atomicAdd(&lcnt[(u32)r0 >> 7], 1u);
        if (r1 >= 0) atomicAdd(&lcnt[(u32)r1 >> 7], 1u);
        if (r2 >= 0) atomicAdd(&lcnt[(u32)r2 >> 7], 1u);
        if (r3 >= 0) atomicAdd(&lcnt[(u32)r3 >> 7], 1u);
    }
    __syncthreads();
    // reserve: lcnt[i] becomes this block's within-bucket write base
    for (int i = tid; i < NBK; i += 256) {
        u32 c = lcnt[i];
        lcnt[i] = c ? atomicAdd(&bcnt[i], c) : 0u;
    }
    __syncthreads();
    // pass B: scatter (chunk re-read is L2-hot)
    for (int e = base + tid; e < lim; e += 1024) {
        int e1 = e + 256, e2 = e + 512, e3 = e + 768;
        int r0 = clampi(load_row(ei, f, e, E), N);
        int c0 = clampi(load_col(ei, f, e, E), N);
        int r1 = -1, c1 = 0, r2 = -1, c2 = 0, r3 = -1, c3 = 0;
        if (e1 < lim) { r1 = clampi(load_row(ei, f, e1, E), N); c1 = clampi(load_col(ei, f, e1, E), N); }
        if (e2 < lim) { r2 = clampi(load_row(ei, f, e2, E), N); c2 = clampi(load_col(ei, f, e2, E), N); }
        if (e3 < lim) { r3 = clampi(load_row(ei, f, e3, E), N); c3 = clampi(load_col(ei, f, e3, E), N); }
        u32 b0 = (u32)r0 >> 7;
        u32 pos = atomicAdd(&lcnt[b0], 1u);
        if (pos < CAP) bdata[(size_t)b0 * CAP + pos] = ((u32)(r0 & (RPB - 1)) << 20) | (u32)c0;
        if (r1 >= 0) {
            u32 b = (u32)r1 >> 7;
            pos = atomicAdd(&lcnt[b], 1u);
            if (pos < CAP) bdata[(size_t)b * CAP + pos] = ((u32)(r1 & (RPB - 1)) << 20) | (u32)c1;
        }
        if (r2 >= 0) {
            u32 b = (u32)r2 >> 7;
            pos = atomicAdd(&lcnt[b], 1u);
            if (pos < CAP) bdata[(size_t)b * CAP + pos] = ((u32)(r2 & (RPB - 1)) << 20) | (u32)c2;
        }
        if (r3 >= 0) {
            u32 b = (u32)r3 >> 7;
            pos = atomicAdd(&lcnt[b], 1u);
            if (pos < CAP) bdata[(size_t)b * CAP + pos] = ((u32)(r3 & (RPB - 1)) << 20) | (u32)c3;
        }
    }
}

// PADDED CSR with per-row (start,end) packed in ONE uint2. Bucket b's records
// live in bdata[b*CAP .. b*CAP+min(bcnt[b],CAP)); ecol region is b*PCAP fixed.
// rend-beg = pdeg (mult of PGRAN, pad -> sentinel col N).
__global__ __launch_bounds__(256) void finalize_k(const u32* __restrict__ bdata,
                                                  const u32* __restrict__ bcnt,
                                                  uint2* __restrict__ rdesc,
                                                  float* __restrict__ dinv,
                                                  u32* __restrict__ ecol,
                                                  int N) {
    __shared__ u32 smc[RPB];
    __shared__ u32 cur[RPB];
    int b = blockIdx.x;
    int tid = threadIdx.x;
    u32 cnt = bcnt[b];
    if (cnt > CAP) cnt = CAP;
    u32 s = (u32)b * CAP;
    u32 t = s + cnt;
    u32 pbase = (u32)b * PCAP;
    if (tid < RPB) smc[tid] = 0;
    __syncthreads();
    for (u32 i = s + tid; i < t; i += 256)
        atomicAdd(&smc[bdata[i] >> 20], 1u);
    __syncthreads();
    u32 deg = (tid < RPB) ? smc[tid] : 0;
    u32 pdeg = (deg + PGRAN - 1) & ~(u32)(PGRAN - 1);
    if (tid < RPB) smc[tid] = pdeg;
    __syncthreads();
    for (int off = 1; off < RPB; off <<= 1) {
        u32 tv = (tid < RPB && tid >= off) ? smc[tid - off] : 0u;
        __syncthreads();
        if (tid < RPB) smc[tid] += tv;
        __syncthreads();
    }
    u32 pexcl = (tid < RPB) ? (smc[tid] - pdeg) : 0;
    if (tid < RPB) {
        int r = b * RPB + tid;
        if (r < N) {
            rdesc[r] = make_uint2(pbase + pexcl, pbase + pexcl + pdeg);
            dinv[r] = rsqrtf((float)(deg + 1u));  // +1 self loop
        }
        cur[tid] = pbase + pexcl;
    }
    __syncthreads();
    for (u32 i = s + tid; i < t; i += 256) {
        u32 rec = bdata[i];
        u32 pos = atomicAdd(&cur[rec >> 20], 1u);
        ecol[pos] = rec & 0xFFFFFu;
    }
    __syncthreads();
    if (tid < RPB) {  // per-row pad tail -> sentinel zero-row
        u32 st = pbase + pexcl;
        for (u32 k = deg; k < pdeg; k++) ecol[st + k] = (u32)N;
    }
}

// Split fp32 W into hi/lo f16 MFMA B-fragments. Blocks 0-7 -> W1, 8-15 -> W2,
// 16 -> W3, 17 -> zero the sentinel rows h[N], h3[N].
__global__ __launch_bounds__(256) void reformat_all(const float* __restrict__ W1,
                                                    const float* __restrict__ W2,
                                                    const float* __restrict__ W3,
                                                    f16* __restrict__ W1h, f16* __restrict__ W1l,
                                                    f16* __restrict__ W2h, f16* __restrict__ W2l,
                                                    f16* __restrict__ W3h, f16* __restrict__ W3l,
                                                    f16* __restrict__ hzero,
                                                    f16* __restrict__ h3zero) {
    if (blockIdx.x == 17) {
        int tix = threadIdx.x;
        if (tix < 128) hzero[tix] = (f16)0;
        else if (tix < 144) h3zero[tix - 128] = (f16)0;
        return;
    }
    const float* W;
    f16 *Wh, *Wl;
    int ntiles, bidx;
    if (blockIdx.x < 8) { W = W1; Wh = W1h; Wl = W1l; ntiles = 8; bidx = blockIdx.x; }
    else if (blockIdx.x < 16) { W = W2; Wh = W2h; Wl = W2l; ntiles = 8; bidx = blockIdx.x - 8; }
    else { W = W3; Wh = W3h; Wl = W3l; ntiles = 1; bidx = 0; }
    int idx = bidx * 256 + threadIdx.x;
    int total = 4 * ntiles * 64;
    if (idx >= total) return;
    int lane = idx & 63;
    int st = idx >> 6;
    int t = st % ntiles;
    int s = st / ntiles;
    int Nc = ntiles * 16;
    int n = t * 16 + (lane & 15);
    int kb = lane >> 4;
    half8 vh, vl;
#pragma unroll
    for (int j = 0; j < 8; j++) {
        float w = W[(size_t)(s * 32 + kb * 8 + j) * Nc + n];
        f16 hi = (f16)w;
        f16 lo = (f16)(w - (float)hi);
        vh[j] = hi;
        vl[j] = lo;
    }
    *(half8*)(Wh + (size_t)idx * 8) = vh;
    *(half8*)(Wl + (size_t)idx * 8) = vl;
}

// ---------------- GEMMs (f16 MFMA 16x16x32, fp32-accurate via splits) --------
// Wh/Wl fragment tables staged in LDS once per block; A prefetched.

// Layer 1: A fp32 [M x 128]; 3 MFMAs; epilogue scales row rr by dinv[rr].
__global__ __launch_bounds__(256) void gemm128_l1(const float* __restrict__ A,
                                                  const f16* __restrict__ Wh,
                                                  const f16* __restrict__ Wl,
                                                  const float* __restrict__ dinv,
                                                  f16* __restrict__ H, int M) {
    __shared__ f16 sBh[2048 * 8];  // 32KB
    __shared__ f16 sBl[2048 * 8];  // 32KB
    for (int i = threadIdx.x; i < 2048; i += 256) {
        *(half8*)(sBh + (size_t)i * 8) = *(const half8*)(Wh + (size_t)i * 8);
        *(half8*)(sBl + (size_t)i * 8) = *(const half8*)(Wl + (size_t)i * 8);
    }
    int wave = threadIdx.x >> 6, lane = threadIdx.x & 63;
    int mbase = blockIdx.x * 64 + wave * 16;
    int mload = mbase + (lane & 15);
    if (mload >= M) mload = M - 1;
    int kq = lane >> 4;
    f32x4 a0[4], a1[4];
#pragma unroll
    for (int s = 0; s < 4; s++) {
        const float* ap = A + (size_t)mload * 128 + s * 32 + kq * 8;
        a0[s] = *(const f32x4*)ap;
        a1[s] = *(const f32x4*)(ap + 4);
    }
    f32x4 acc[8];
#pragma unroll
    for (int t = 0; t < 8; t++) acc[t] = (f32x4){0.f, 0.f, 0.f, 0.f};
    __syncthreads();
#pragma unroll
    for (int s = 0; s < 4; s++) {
        half8 ah, al;
#pragma unroll
        for (int j = 0; j < 4; j++) {
            float v = a0[s][j];
            f16 hi = (f16)v;
            ah[j] = hi;
            al[j] = (f16)(v - (float)hi);
            float w = a1[s][j];
            f16 wi = (f16)w;
            ah[j + 4] = wi;
            al[j + 4] = (f16)(w - (float)wi);
        }
#pragma unroll
        for (int t = 0; t < 8; t++) {
            half8 bh = *(const half8*)(sBh + (size_t)((s * 8 + t) * 64 + lane) * 8);
            half8 bl = *(const half8*)(sBl + (size_t)((s * 8 + t) * 64 + lane) * 8);
            acc[t] = __builtin_amdgcn_mfma_f32_16x16x32_f16(ah, bh, acc[t], 0, 0, 0);
            acc[t] = __builtin_amdgcn_mfma_f32_16x16x32_f16(ah, bl, acc[t], 0, 0, 0);
            acc[t] = __builtin_amdgcn_mfma_f32_16x16x32_f16(al, bh, acc[t], 0, 0, 0);
        }
    }
    int coln = lane & 15;
    int rbase = mbase + ((lane >> 4) << 2);
    float dsc[4];
#pragma unroll
    for (int i = 0; i < 4; i++) {
        int rr = rbase + i;
        dsc[i] = dinv[rr < M ? rr : M - 1];
    }
#pragma unroll
    for (int t = 0; t < 8; t++) {
#pragma unroll
        for (int i = 0; i < 4; i++) {
            int rr = rbase + i;
            if (rr < M) H[(size_t)rr * 128 + t * 16 + coln] = (f16)(acc[t][i] * dsc[i]);
        }
    }
}

// Layer 2: A f16 (pre-scaled act') [M x 128]; 2 MFMAs.
__global__ __launch_bounds__(256) void gemm128_l2(const f16* __restrict__ A,
                                                  const f16* __restrict__ Wh,
                                                  const f16* __restrict__ Wl,
                                                  f16* __restrict__ H, int M) {
    __shared__ f16 sBh[2048 * 8];
    __shared__ f16 sBl[2048 * 8];
    for (int i = threadIdx.x; i < 2048; i += 256) {
        *(half8*)(sBh + (size_t)i * 8) = *(const half8*)(Wh + (size_t)i * 8);
        *(half8*)(sBl + (size_t)i * 8) = *(const half8*)(Wl + (size_t)i * 8);
    }
    int wave = threadIdx.x >> 6, lane = threadIdx.x & 63;
    int mbase = blockIdx.x * 64 + wave * 16;
    int mload = mbase + (lane & 15);
    if (mload >= M) mload = M - 1;
    int kq = lane >> 4;
    half8 a[4];
#pragma unroll
    for (int s = 0; s < 4; s++)
        a[s] = *(const half8*)(A + (size_t)mload * 128 + s * 32 + kq * 8);
    f32x4 acc[8];
#pragma unroll
    for (int t = 0; t < 8; t++) acc[t] = (f32x4){0.f, 0.f, 0.f, 0.f};
    __syncthreads();
#pragma unroll
    for (int s = 0; s < 4; s++) {
#pragma unroll
        for (int t = 0; t < 8; t++) {
            half8 bh = *(const half8*)(sBh + (size_t)((s * 8 + t) * 64 + lane) * 8);
            half8 bl = *(const half8*)(sBl + (size_t)((s * 8 + t) * 64 + lane) * 8);
            acc[t] = __builtin_amdgcn_mfma_f32_16x16x32_f16(a[s], bh, acc[t], 0, 0, 0);
            acc[t] = __builtin_amdgcn_mfma_f32_16x16x32_f16(a[s], bl, acc[t], 0, 0, 0);
        }
    }
    int coln = lane & 15;
    int rbase = mbase + ((lane >> 4) << 2);
#pragma unroll
    for (int t = 0; t < 8; t++) {
#pragma unroll
        for (int i = 0; i < 4; i++) {
            int rr = rbase + i;
            if (rr < M) H[(size_t)rr * 128 + t * 16 + coln] = (f16)acc[t][i];
        }
    }
}

// Layer 3: A f16 (pre-scaled) [M x 128] -> H3' f16 [M x 16].
__global__ __launch_bounds__(256) void gemm16(const f16* __restrict__ A,
                                              const f16* __restrict__ Wh,
                                              const f16* __restrict__ Wl,
                                              f16* __restrict__ H, int M) {
    __shared__ f16 sBh[256 * 8];  // 4KB
    __shared__ f16 sBl[256 * 8];  // 4KB
    if (threadIdx.x < 256) {
        int i = threadIdx.x;
        *(half8*)(sBh + (size_t)i * 8) = *(const half8*)(Wh + (size_t)i * 8);
        *(half8*)(sBl + (size_t)i * 8) = *(const half8*)(Wl + (size_t)i * 8);
    }
    int wave = threadIdx.x >> 6, lane = threadIdx.x & 63;
    int mbase = blockIdx.x * 64 + wave * 16;
    int mload = mbase + (lane & 15);
    if (mload >= M) mload = M - 1;
    int kq = lane >> 4;
    half8 a[4];
#pragma unroll
    for (int s = 0; s < 4; s++)
        a[s] = *(const half8*)(A + (size_t)mload * 128 + s * 32 + kq * 8);
    f32x4 acc = (f32x4){0.f, 0.f, 0.f, 0.f};
    __syncthreads();
#pragma unroll
    for (int s = 0; s < 4; s++) {
        half8 bh = *(const half8*)(sBh + (size_t)(s * 64 + lane) * 8);
        half8 bl = *(const half8*)(sBl + (size_t)(s * 64 + lane) * 8);
        acc = __builtin_amdgcn_mfma_f32_16x16x32_f16(a[s], bh, acc, 0, 0, 0);
        acc = __builtin_amdgcn_mfma_f32_16x16x32_f16(a[s], bl, acc, 0, 0, 0);
    }
    int coln = lane & 15;
    int rbase = mbase + ((lane >> 4) << 2);
#pragma unroll
    for (int i = 0; i < 4; i++) {
        int rr = rbase + i;
        if (rr < M) H[(size_t)rr * 16 + coln] = (f16)acc[i];
    }
}

// ---------------- aggregation ----------------
// One wave per row (R3-verified roofline schedule: ~3.87 TB/s fill, the
// random-256B-gather BW ceiling). uint2 descriptor + hoisted epilogue loads.
__global__ __launch_bounds__(256) void agg128(const f16* __restrict__ h,
                                              const u32* __restrict__ ecol,
                                              const uint2* __restrict__ rdesc,
                                              const float* __restrict__ dinv,
                                              const float* __restrict__ bias,
                                              f16* __restrict__ out, int M) {
    int lane = threadIdx.x & 63;
    int wave = __builtin_amdgcn_readfirstlane(threadIdx.x >> 6);
    int r = blockIdx.x * 4 + wave;
    if (r >= M) return;
    uint2 d = rdesc[r];
    u32 e = (u32)__builtin_amdgcn_readfirstlane((int)d.x);
    u32 end = (u32)__builtin_amdgcn_readfirstlane((int)d.y);
    float dr = dinv[r];
    const char* hb = (const char*)h;
    u32 loff = (u32)lane << 2;
    float2 bb = ((const float2*)bias)[lane];
    half2_t vs = *(const half2_t*)(hb + (((u32)r << 8) + loff));
    float ax0 = 0, ay0 = 0, ax1 = 0, ay1 = 0, ax2 = 0, ay2 = 0, ax3 = 0, ay3 = 0;
    for (; e + 16 <= end; e += 16) {
        const u32* ep = ecol + e;
        u32 c[16];
#pragma unroll
        for (int j = 0; j < 16; j++) c[j] = ep[j];
        half2_t v[16];
#pragma unroll
        for (int j = 0; j < 16; j++)
            v[j] = *(const half2_t*)(hb + ((c[j] << 8) + loff));
#pragma unroll
        for (int j = 0; j < 16; j += 4) {
            ax0 = fmaf((float)v[j][0],     dr, ax0); ay0 = fmaf((float)v[j][1],     dr, ay0);
            ax1 = fmaf((float)v[j + 1][0], dr, ax1); ay1 = fmaf((float)v[j + 1][1], dr, ay1);
            ax2 = fmaf((float)v[j + 2][0], dr, ax2); ay2 = fmaf((float)v[j + 2][1], dr, ay2);
            ax3 = fmaf((float)v[j + 3][0], dr, ax3); ay3 = fmaf((float)v[j + 3][1], dr, ay3);
        }
    }
    for (; e < end; e += 4) {  // tail: 0-3 iterations of 4 (pdeg mult of 4)
        const u32* ep = ecol + e;
        u32 c0 = ep[0], c1 = ep[1], c2 = ep[2], c3 = ep[3];
        half2_t v0 = *(const half2_t*)(hb + ((c0 << 8) + loff));
        half2_t v1 = *(const half2_t*)(hb + ((c1 << 8) + loff));
        half2_t v2 = *(const half2_t*)(hb + ((c2 << 8) + loff));
        half2_t v3 = *(const half2_t*)(hb + ((c3 << 8) + loff));
        ax0 = fmaf((float)v0[0], dr, ax0); ay0 = fmaf((float)v0[1], dr, ay0);
        ax1 = fmaf((float)v1[0], dr, ax1); ay1 = fmaf((float)v1[1], dr, ay1);
        ax2 = fmaf((float)v2[0], dr, ax2); ay2 = fmaf((float)v2[1], dr, ay2);
        ax3 = fmaf((float)v3[0], dr, ax3); ay3 = fmaf((float)v3[1], dr, ay3);
    }
    float ax = ((ax0 + ax1) + (ax2 + ax3)) + fmaf((float)vs[0], dr, bb.x);
    float ay = ((ay0 + ay1) + (ay2 + ay3)) + fmaf((float)vs[1], dr, bb.y);
    ax = fmaxf(ax, 0.f) * dr;  // pre-scale for next layer's gather
    ay = fmaxf(ay, 0.f) * dr;
    half2_t o;
    o[0] = (f16)ax;
    o[1] = (f16)ay;
    ((half2_t*)out)[(size_t)r * 64 + lane] = o;
}

// 16 lanes per row; h3' pre-scaled; padded CSR (PGRAN=4) -> 8-batches + one
// optional 4-batch tail; uint2 descriptor + hoisted self/bias loads.
__global__ __launch_bounds__(256) void agg16_lsm(const f16* __restrict__ h3,
                                                 const u32* __restrict__ ecol,
                                                 const uint2* __restrict__ rdesc,
                                                 const float* __restrict__ dinv,
                                                 const float* __restrict__ bias,
                                                 float* __restrict__ out, int M) {
    int g = threadIdx.x >> 4, l = threadIdx.x & 15;
    int r = blockIdx.x * 16 + g;
    if (r >= M) return;
    uint2 d = rdesc[r];
    u32 beg = d.x, end = d.y;
    float dr = dinv[r];
    float bl = bias[l];
    float self = (float)h3[(size_t)r * 16 + l];
    float a0 = 0.f, a1 = 0.f, a2 = 0.f, a3 = 0.f;
    u32 e = beg;
    for (; e + 8 <= end; e += 8) {
        u32 c[8];
#pragma unroll
        for (int j = 0; j < 8; j++) c[j] = ecol[e + j];
        f16 v[8];
#pragma unroll
        for (int j = 0; j < 8; j++) v[j] = h3[(size_t)c[j] * 16 + l];
        a0 += (float)v[0] + (float)v[4];
        a1 += (float)v[1] + (float)v[5];
        a2 += (float)v[2] + (float)v[6];
        a3 += (float)v[3] + (float)v[7];
    }
    if (e < end) {  // remainder is exactly 4
        u32 c[4];
#pragma unroll
        for (int j = 0; j < 4; j++) c[j] = ecol[e + j];
        f16 v[4];
#pragma unroll
        for (int j = 0; j < 4; j++) v[j] = h3[(size_t)c[j] * 16 + l];
        a0 += (float)v[0];
        a1 += (float)v[1];
        a2 += (float)v[2];
        a3 += (float)v[3];
    }
    float acc = (((a0 + a1) + (a2 + a3)) + self) * dr + bl;
    float m = acc;
#pragma unroll
    for (int o = 8; o >= 1; o >>= 1) m = fmaxf(m, __shfl_xor(m, o, 16));
    float ex = expf(acc - m);
    float s = ex;
#pragma unroll
    for (int o = 8; o >= 1; o >>= 1) s += __shfl_xor(s, o, 16);
    out[(size_t)r * 16 + l] = acc - m - logf(s);
}

// ---------------- launch ----------------

extern "C" void kernel_launch(void* const* d_in, const int* in_sizes, int n_in,
                              void* d_out, int out_size, void* d_ws, size_t ws_size,
                              hipStream_t stream) {
    const float* x = (const float*)d_in[0];
    const int* ei = (const int*)d_in[1];
    const float* W1 = (const float*)d_in[2];
    const float* b1 = (const float*)d_in[3];
    const float* W2 = (const float*)d_in[4];
    const float* b2 = (const float*)d_in[5];
    const float* W3 = (const float*)d_in[6];
    const float* b3 = (const float*)d_in[7];
    int N = in_sizes[0] / D_IN;
    int E = in_sizes[1] / 2;

    int NBK = (N + RPB - 1) / RPB;     // 782 row-buckets (<= MAXBUCK)
    int NB = (E + CHUNK - 1) / CHUNK;  // 157 scatter blocks

    char* p = (char*)d_ws;
    auto alloc = [&](size_t bytes) -> void* {
        void* q = (void*)p;
        p += (bytes + 255) & ~(size_t)255;
        return q;
    };
    u32* bcnt = (u32*)alloc((size_t)NBK * 4);
    float* dinv = (float*)alloc((size_t)N * 4);
    uint2* rdesc = (uint2*)alloc((size_t)(N + 1) * 8);
    u32* bdata = (u32*)alloc((size_t)NBK * CAP * 4);
    u32* ecol = (u32*)alloc((size_t)NBK * PCAP * 4 + 256);
    f16* wf1h = (f16*)alloc(16384 * 2);
    f16* wf1l = (f16*)alloc(16384 * 2);
    f16* wf2h = (f16*)alloc(16384 * 2);
    f16* wf2l = (f16*)alloc(16384 * 2);
    f16* wf3h = (f16*)alloc(2048 * 2);
    f16* wf3l = (f16*)alloc(2048 * 2);
    f16* h = (f16*)alloc((size_t)(N + 1) * 128 * 2);   // +1 sentinel zero row
    f16* act = (f16*)alloc((size_t)N * 128 * 2);
    f16* h3 = (f16*)alloc((size_t)(N + 1) * 16 * 2);   // +1 sentinel zero row
    (void)ws_size; (void)n_in; (void)out_size;

    hipMemsetAsync(bcnt, 0, (size_t)NBK * 4, stream);

    scatter_k<<<NB, 256, 0, stream>>>(ei, bcnt, bdata, E, N, NBK);
    finalize_k<<<NBK, 256, 0, stream>>>(bdata, bcnt, rdesc, dinv, ecol, N);

    reformat_all<<<18, 256, 0, stream>>>(W1, W2, W3, wf1h, wf1l, wf2h, wf2l,
                                         wf3h, wf3l,
                                         h + (size_t)N * 128,
                                         h3 + (size_t)N * 16);

    int gb = (N + 63) / 64;
    int ab = (N + 3) / 4;
    gemm128_l1<<<gb, 256, 0, stream>>>(x, wf1h, wf1l, dinv, h, N);
    agg128<<<ab, 256, 0, stream>>>(h, ecol, rdesc, dinv, b1, act, N);
    gemm128_l2<<<gb, 256, 0, stream>>>(act, wf2h, wf2l, h, N);
    agg128<<<ab, 256, 0, stream>>>(h, ecol, rdesc, dinv, b2, act, N);
    gemm16<<<gb, 256, 0, stream>>>(act, wf3h, wf3l, h3, N);
    agg16_lsm<<<(N + 15) / 16, 256, 0, stream>>>(h3, ecol, rdesc,
                                                 dinv, b3, (float*)d_out, N);
}

// Round 6
// 332.819 us; speedup vs baseline: 1.1730x; 1.0044x over previous
//
#include <hip/hip_runtime.h>

typedef unsigned int u32;
typedef _Float16 f16;
typedef __attribute__((ext_vector_type(8))) _Float16 half8;
typedef __attribute__((ext_vector_type(2))) _Float16 half2_t;
typedef __attribute__((ext_vector_type(4))) float f32x4;

#define D_IN 128
#define D_HID 128
#define D_OUT 16
#define RPB 128        // rows per bucket (lr fits in 7 bits; c < 2^20)
#define MAXBUCK 1024   // supports N <= 131072
#define CHUNK 10240    // edges per scatter block (157 blocks at E=1.6M)
#define PGRAN 4        // pad each row's edge run to a multiple of 4
#define CAP 3072       // bdata capacity per bucket (mean 2046, +22 sigma)
#define PCAP 3584      // ecol capacity per bucket; >= CAP + 3*128 pad

// ---------------- preprocessing ----------------

__device__ inline int load_row(const int* ei, u32 f, int e, int E) {
    return f ? ei[e] : ei[2 * e];
}
__device__ inline int load_col(const int* ei, u32 f, int e, int E) {
    return f ? ei[E + e] : ei[2 * E + 2 * e];
}
__device__ inline int clampi(int v, int n) {
    v = v < 0 ? 0 : v;
    return v >= n ? n - 1 : v;
}

// R15 single scatter pass + R16: reformat fused in as 18 trailing blocks
// (independent work; scatter is latency-bound at 157 blocks -> free capacity).
// Scatter blocks [0,NB): per-block layout detect, LDS hist, ONE global
// atomicAdd per (bucket,block) reserve, L2-hot re-read scatter into the
// bucket's FIXED region [b*CAP, b*CAP+CAP). Record = (r&127)<<20 | c.
__global__ __launch_bounds__(256) void scatter_k(const int* __restrict__ ei,
                                                 u32* __restrict__ bcnt,
                                                 u32* __restrict__ bdata,
                                                 int E, int N, int NBK, int NB,
                                                 const float* __restrict__ W1,
                                                 const float* __restrict__ W2,
                                                 const float* __restrict__ W3,
                                                 f16* __restrict__ W1h, f16* __restrict__ W1l,
                                                 f16* __restrict__ W2h, f16* __restrict__ W2l,
                                                 f16* __restrict__ W3h, f16* __restrict__ W3l,
                                                 f16* __restrict__ hzero,
                                                 f16* __restrict__ h3zero) {
    if (blockIdx.x >= (u32)NB) {  // ---- fused reformat path ----
        int rb = blockIdx.x - NB;
        if (rb == 17) {
            int tix = threadIdx.x;
            if (tix < 128) hzero[tix] = (f16)0;
            else if (tix < 144) h3zero[tix - 128] = (f16)0;
            return;
        }
        const float* W;
        f16 *Wh, *Wl;
        int ntiles, bidx;
        if (rb < 8) { W = W1; Wh = W1h; Wl = W1l; ntiles = 8; bidx = rb; }
        else if (rb < 16) { W = W2; Wh = W2h; Wl = W2l; ntiles = 8; bidx = rb - 8; }
        else { W = W3; Wh = W3h; Wl = W3l; ntiles = 1; bidx = 0; }
        int idx = bidx * 256 + threadIdx.x;
        int total = 4 * ntiles * 64;
        if (idx >= total) return;
        int lane = idx & 63;
        int st = idx >> 6;
        int t = st % ntiles;
        int s = st / ntiles;
        int Nc = ntiles * 16;
        int n = t * 16 + (lane & 15);
        int kb = lane >> 4;
        half8 vh, vl;
#pragma unroll
        for (int j = 0; j < 8; j++) {
            float w = W[(size_t)(s * 32 + kb * 8 + j) * Nc + n];
            f16 hi = (f16)w;
            f16 lo = (f16)(w - (float)hi);
            vh[j] = hi;
            vl[j] = lo;
        }
        *(half8*)(Wh + (size_t)idx * 8) = vh;
        *(half8*)(Wl + (size_t)idx * 8) = vl;
        return;
    }
    // ---- scatter path ----
    __shared__ u32 lcnt[MAXBUCK];
    __shared__ u32 lflag;
    int tid = threadIdx.x;
    if (tid == 0) lflag = 0;
    for (int i = tid; i < NBK; i += 256) lcnt[i] = 0;
    __syncthreads();
    // layout detect: any nonzero odd 32-bit word => int32 layout
    int nw = (2 * E < 8192) ? 2 * E : 8192;
    for (int k = tid * 2 + 1; k < nw; k += 512)
        if (ei[k] != 0) atomicOr(&lflag, 1u);
    __syncthreads();
    u32 f = lflag;
    int base = blockIdx.x * CHUNK;
    int lim = base + CHUNK < E ? base + CHUNK : E;
    // pass A: count (4-way unrolled so 4 strided loads are in flight)
    for (int e = base + tid; e < lim; e += 1024) {
        int e1 = e + 256, e2 = e + 512, e3 = e + 768;
        int r0 = clampi(load_row(ei, f, e, E), N);
        int r1 = (e1 < lim) ? clampi(load_row(ei, f, e1, E), N) : -1;
        int r2 = (e2 < lim) ? clampi(load_row(ei, f, e2, E), N) : -1;
        int r3 = (e3 < lim) ? clampi(load_row(ei, f, e3, E), N) : -1;
        atomicAdd(&lcnt[(u32)r0 >> 7], 1u);
        if (r1 >= 0) atomicAdd(&lcnt[(u32)r1 >> 7], 1u);
        if (r2 >= 0) atomicAdd(&lcnt[(u32)r2 >> 7], 1u);
        if (r3 >= 0) atomicAdd(&lcnt[(u32)r3 >> 7], 1u);
    }
    __syncthreads();
    // reserve: lcnt[i] becomes this block's within-bucket write base
    for (int i = tid; i < NBK; i += 256) {
        u32 c = lcnt[i];
        lcnt[i] = c ? atomicAdd(&bcnt[i], c) : 0u;
    }
    __syncthreads();
    // pass B: scatter (chunk re-read is L2-hot)
    for (int e = base + tid; e < lim; e += 1024) {
        int e1 = e + 256, e2 = e + 512, e3 = e + 768;
        int r0 = clampi(load_row(ei, f, e, E), N);
        int c0 = clampi(load_col(ei, f, e, E), N);
        int r1 = -1, c1 = 0, r2 = -1, c2 = 0, r3 = -1, c3 = 0;
        if (e1 < lim) { r1 = clampi(load_row(ei, f, e1, E), N); c1 = clampi(load_col(ei, f, e1, E), N); }
        if (e2 < lim) { r2 = clampi(load_row(ei, f, e2, E), N); c2 = clampi(load_col(ei, f, e2, E), N); }
        if (e3 < lim) { r3 = clampi(load_row(ei, f, e3, E), N); c3 = clampi(load_col(ei, f, e3, E), N); }
        u32 b0 = (u32)r0 >> 7;
        u32 pos = atomicAdd(&lcnt[b0], 1u);
        if (pos < CAP) bdata[(size_t)b0 * CAP + pos] = ((u32)(r0 & (RPB - 1)) << 20) | (u32)c0;
        if (r1 >= 0) {
            u32 b = (u32)r1 >> 7;
            pos = atomicAdd(&lcnt[b], 1u);
            if (pos < CAP) bdata[(size_t)b * CAP + pos] = ((u32)(r1 & (RPB - 1)) << 20) | (u32)c1;
        }
        if (r2 >= 0) {
            u32 b = (u32)r2 >> 7;
            pos = atomicAdd(&lcnt[b], 1u);
            if (pos < CAP) bdata[(size_t)b * CAP + pos] = ((u32)(r2 & (RPB - 1)) << 20) | (u32)c2;
        }
        if (r3 >= 0) {
            u32 b = (u32)r3 >> 7;
            pos = atomicAdd(&lcnt[b], 1u);
            if (pos < CAP) bdata[(size_t)b * CAP + pos] = ((u32)(r3 & (RPB - 1)) << 20) | (u32)c3;
        }
    }
}

// PADDED CSR with per-row (start,end) packed in ONE uint2. Bucket b's records
// live in bdata[b*CAP .. b*CAP+min(bcnt[b],CAP)); ecol region is b*PCAP fixed.
__global__ __launch_bounds__(256) void finalize_k(const u32* __restrict__ bdata,
                                                  const u32* __restrict__ bcnt,
                                                  uint2* __restrict__ rdesc,
                                                  float* __restrict__ dinv,
                                                  u32* __restrict__ ecol,
                                                  int N) {
    __shared__ u32 smc[RPB];
    __shared__ u32 cur[RPB];
    int b = blockIdx.x;
    int tid = threadIdx.x;
    u32 cnt = bcnt[b];
    if (cnt > CAP) cnt = CAP;
    u32 s = (u32)b * CAP;
    u32 t = s + cnt;
    u32 pbase = (u32)b * PCAP;
    if (tid < RPB) smc[tid] = 0;
    __syncthreads();
    for (u32 i = s + tid; i < t; i += 256)
        atomicAdd(&smc[bdata[i] >> 20], 1u);
    __syncthreads();
    u32 deg = (tid < RPB) ? smc[tid] : 0;
    u32 pdeg = (deg + PGRAN - 1) & ~(u32)(PGRAN - 1);
    if (tid < RPB) smc[tid] = pdeg;
    __syncthreads();
    for (int off = 1; off < RPB; off <<= 1) {
        u32 tv = (tid < RPB && tid >= off) ? smc[tid - off] : 0u;
        __syncthreads();
        if (tid < RPB) smc[tid] += tv;
        __syncthreads();
    }
    u32 pexcl = (tid < RPB) ? (smc[tid] - pdeg) : 0;
    if (tid < RPB) {
        int r = b * RPB + tid;
        if (r < N) {
            rdesc[r] = make_uint2(pbase + pexcl, pbase + pexcl + pdeg);
            dinv[r] = rsqrtf((float)(deg + 1u));  // +1 self loop
        }
        cur[tid] = pbase + pexcl;
    }
    __syncthreads();
    for (u32 i = s + tid; i < t; i += 256) {
        u32 rec = bdata[i];
        u32 pos = atomicAdd(&cur[rec >> 20], 1u);
        ecol[pos] = rec & 0xFFFFFu;
    }
    __syncthreads();
    if (tid < RPB) {  // per-row pad tail -> sentinel zero-row
        u32 st = pbase + pexcl;
        for (u32 k = deg; k < pdeg; k++) ecol[st + k] = (u32)N;
    }
}

// ---------------- GEMMs (f16 MFMA 16x16x32, fp32-accurate via splits) --------
// R16: 2 M-tiles per wave (128 rows/block, grid halved to 782). Each (s,t)
// B-fragment pair is ds_read ONCE and feeds both tiles' MFMAs -> inner loop
// goes from LDS-read-bound (2 ds_read_b128 : 3 MFMA, ~12cy vs ~5cy each) to
// MFMA-bound (2 : 6). Staging traffic also halves (782 x 64KB vs 1563 x).

// Layer 1: A fp32 [M x 128]; 3 MFMAs/fragment; epilogue scales by dinv[rr].
__global__ __launch_bounds__(256) void gemm128_l1(const float* __restrict__ A,
                                                  const f16* __restrict__ Wh,
                                                  const f16* __restrict__ Wl,
                                                  const float* __restrict__ dinv,
                                                  f16* __restrict__ H, int M) {
    __shared__ f16 sBh[2048 * 8];  // 32KB
    __shared__ f16 sBl[2048 * 8];  // 32KB
    for (int i = threadIdx.x; i < 2048; i += 256) {
        *(half8*)(sBh + (size_t)i * 8) = *(const half8*)(Wh + (size_t)i * 8);
        *(half8*)(sBl + (size_t)i * 8) = *(const half8*)(Wl + (size_t)i * 8);
    }
    int wave = threadIdx.x >> 6, lane = threadIdx.x & 63;
    int kq = lane >> 4;
    int mb[2], ml[2];
    mb[0] = blockIdx.x * 128 + wave * 16;
    mb[1] = mb[0] + 64;
#pragma unroll
    for (int t2 = 0; t2 < 2; t2++) {
        ml[t2] = mb[t2] + (lane & 15);
        if (ml[t2] >= M) ml[t2] = M - 1;
    }
    f32x4 a0[2][4], a1[2][4];
#pragma unroll
    for (int t2 = 0; t2 < 2; t2++)
#pragma unroll
        for (int s = 0; s < 4; s++) {
            const float* ap = A + (size_t)ml[t2] * 128 + s * 32 + kq * 8;
            a0[t2][s] = *(const f32x4*)ap;
            a1[t2][s] = *(const f32x4*)(ap + 4);
        }
    f32x4 acc[2][8];
#pragma unroll
    for (int t2 = 0; t2 < 2; t2++)
#pragma unroll
        for (int t = 0; t < 8; t++) acc[t2][t] = (f32x4){0.f, 0.f, 0.f, 0.f};
    __syncthreads();
#pragma unroll
    for (int s = 0; s < 4; s++) {
        half8 ah[2], al[2];
#pragma unroll
        for (int t2 = 0; t2 < 2; t2++)
#pragma unroll
            for (int j = 0; j < 4; j++) {
                float v = a0[t2][s][j];
                f16 hi = (f16)v;
                ah[t2][j] = hi;
                al[t2][j] = (f16)(v - (float)hi);
                float w = a1[t2][s][j];
                f16 wi = (f16)w;
                ah[t2][j + 4] = wi;
                al[t2][j + 4] = (f16)(w - (float)wi);
            }
#pragma unroll
        for (int t = 0; t < 8; t++) {
            half8 bh = *(const half8*)(sBh + (size_t)((s * 8 + t) * 64 + lane) * 8);
            half8 bl = *(const half8*)(sBl + (size_t)((s * 8 + t) * 64 + lane) * 8);
            acc[0][t] = __builtin_amdgcn_mfma_f32_16x16x32_f16(ah[0], bh, acc[0][t], 0, 0, 0);
            acc[0][t] = __builtin_amdgcn_mfma_f32_16x16x32_f16(ah[0], bl, acc[0][t], 0, 0, 0);
            acc[0][t] = __builtin_amdgcn_mfma_f32_16x16x32_f16(al[0], bh, acc[0][t], 0, 0, 0);
            acc[1][t] = __builtin_amdgcn_mfma_f32_16x16x32_f16(ah[1], bh, acc[1][t], 0, 0, 0);
            acc[1][t] = __builtin_amdgcn_mfma_f32_16x16x32_f16(ah[1], bl, acc[1][t], 0, 0, 0);
            acc[1][t] = __builtin_amdgcn_mfma_f32_16x16x32_f16(al[1], bh, acc[1][t], 0, 0, 0);
        }
    }
    int coln = lane & 15;
#pragma unroll
    for (int t2 = 0; t2 < 2; t2++) {
        int rbase = mb[t2] + ((lane >> 4) << 2);
        float dsc[4];
#pragma unroll
        for (int i = 0; i < 4; i++) {
            int rr = rbase + i;
            dsc[i] = dinv[rr < M ? rr : M - 1];
        }
#pragma unroll
        for (int t = 0; t < 8; t++) {
#pragma unroll
            for (int i = 0; i < 4; i++) {
                int rr = rbase + i;
                if (rr < M) H[(size_t)rr * 128 + t * 16 + coln] = (f16)(acc[t2][t][i] * dsc[i]);
            }
        }
    }
}

// Layer 2: A f16 (pre-scaled act') [M x 128]; 2 MFMAs/fragment.
__global__ __launch_bounds__(256) void gemm128_l2(const f16* __restrict__ A,
                                                  const f16* __restrict__ Wh,
                                                  const f16* __restrict__ Wl,
                                                  f16* __restrict__ H, int M) {
    __shared__ f16 sBh[2048 * 8];
    __shared__ f16 sBl[2048 * 8];
    for (int i = threadIdx.x; i < 2048; i += 256) {
        *(half8*)(sBh + (size_t)i * 8) = *(const half8*)(Wh + (size_t)i * 8);
        *(half8*)(sBl + (size_t)i * 8) = *(const half8*)(Wl + (size_t)i * 8);
    }
    int wave = threadIdx.x >> 6, lane = threadIdx.x & 63;
    int kq = lane >> 4;
    int mb[2], ml[2];
    mb[0] = blockIdx.x * 128 + wave * 16;
    mb[1] = mb[0] + 64;
#pragma unroll
    for (int t2 = 0; t2 < 2; t2++) {
        ml[t2] = mb[t2] + (lane & 15);
        if (ml[t2] >= M) ml[t2] = M - 1;
    }
    half8 a[2][4];
#pragma unroll
    for (int t2 = 0; t2 < 2; t2++)
#pragma unroll
        for (int s = 0; s < 4; s++)
            a[t2][s] = *(const half8*)(A + (size_t)ml[t2] * 128 + s * 32 + kq * 8);
    f32x4 acc[2][8];
#pragma unroll
    for (int t2 = 0; t2 < 2; t2++)
#pragma unroll
        for (int t = 0; t < 8; t++) acc[t2][t] = (f32x4){0.f, 0.f, 0.f, 0.f};
    __syncthreads();
#pragma unroll
    for (int s = 0; s < 4; s++) {
#pragma unroll
        for (int t = 0; t < 8; t++) {
            half8 bh = *(const half8*)(sBh + (size_t)((s * 8 + t) * 64 + lane) * 8);
            half8 bl = *(const half8*)(sBl + (size_t)((s * 8 + t) * 64 + lane) * 8);
            acc[0][t] = __builtin_amdgcn_mfma_f32_16x16x32_f16(a[0][s], bh, acc[0][t], 0, 0, 0);
            acc[0][t] = __builtin_amdgcn_mfma_f32_16x16x32_f16(a[0][s], bl, acc[0][t], 0, 0, 0);
            acc[1][t] = __builtin_amdgcn_mfma_f32_16x16x32_f16(a[1][s], bh, acc[1][t], 0, 0, 0);
            acc[1][t] = __builtin_amdgcn_mfma_f32_16x16x32_f16(a[1][s], bl, acc[1][t], 0, 0, 0);
        }
    }
    int coln = lane & 15;
#pragma unroll
    for (int t2 = 0; t2 < 2; t2++) {
        int rbase = mb[t2] + ((lane >> 4) << 2);
#pragma unroll
        for (int t = 0; t < 8; t++) {
#pragma unroll
            for (int i = 0; i < 4; i++) {
                int rr = rbase + i;
                if (rr < M) H[(size_t)rr * 128 + t * 16 + coln] = (f16)acc[t2][t][i];
            }
        }
    }
}

// Layer 3: A f16 (pre-scaled) [M x 128] -> H3' f16 [M x 16]. Memory-bound
// streaming; 8KB LDS -> occupancy not LDS-limited; unchanged structure.
__global__ __launch_bounds__(256) void gemm16(const f16* __restrict__ A,
                                              const f16* __restrict__ Wh,
                                              const f16* __restrict__ Wl,
                                              f16* __restrict__ H, int M) {
    __shared__ f16 sBh[256 * 8];  // 4KB
    __shared__ f16 sBl[256 * 8];  // 4KB
    if (threadIdx.x < 256) {
        int i = threadIdx.x;
        *(half8*)(sBh + (size_t)i * 8) = *(const half8*)(Wh + (size_t)i * 8);
        *(half8*)(sBl + (size_t)i * 8) = *(const half8*)(Wl + (size_t)i * 8);
    }
    int wave = threadIdx.x >> 6, lane = threadIdx.x & 63;
    int mbase = blockIdx.x * 64 + wave * 16;
    int mload = mbase + (lane & 15);
    if (mload >= M) mload = M - 1;
    int kq = lane >> 4;
    half8 a[4];
#pragma unroll
    for (int s = 0; s < 4; s++)
        a[s] = *(const half8*)(A + (size_t)mload * 128 + s * 32 + kq * 8);
    f32x4 acc = (f32x4){0.f, 0.f, 0.f, 0.f};
    __syncthreads();
#pragma unroll
    for (int s = 0; s < 4; s++) {
        half8 bh = *(const half8*)(sBh + (size_t)(s * 64 + lane) * 8);
        half8 bl = *(const half8*)(sBl + (size_t)(s * 64 + lane) * 8);
        acc = __builtin_amdgcn_mfma_f32_16x16x32_f16(a[s], bh, acc, 0, 0, 0);
        acc = __builtin_amdgcn_mfma_f32_16x16x32_f16(a[s], bl, acc, 0, 0, 0);
    }
    int coln = lane & 15;
    int rbase = mbase + ((lane >> 4) << 2);
#pragma unroll
    for (int i = 0; i < 4; i++) {
        int rr = rbase + i;
        if (rr < M) H[(size_t)rr * 16 + coln] = (f16)acc[i];
    }
}

// ---------------- aggregation ----------------
// One wave per row (R3-verified roofline schedule: ~3.87 TB/s fill, the
// random-256B-gather BW ceiling). uint2 descriptor + hoisted epilogue loads.
// DO NOT TOUCH — two alternative schedules both landed at the same fill rate.
__global__ __launch_bounds__(256) void agg128(const f16* __restrict__ h,
                                              const u32* __restrict__ ecol,
                                              const uint2* __restrict__ rdesc,
                                              const float* __restrict__ dinv,
                                              const float* __restrict__ bias,
                                              f16* __restrict__ out, int M) {
    int lane = threadIdx.x & 63;
    int wave = __builtin_amdgcn_readfirstlane(threadIdx.x >> 6);
    int r = blockIdx.x * 4 + wave;
    if (r >= M) return;
    uint2 d = rdesc[r];
    u32 e = (u32)__builtin_amdgcn_readfirstlane((int)d.x);
    u32 end = (u32)__builtin_amdgcn_readfirstlane((int)d.y);
    float dr = dinv[r];
    const char* hb = (const char*)h;
    u32 loff = (u32)lane << 2;
    float2 bb = ((const float2*)bias)[lane];
    half2_t vs = *(const half2_t*)(hb + (((u32)r << 8) + loff));
    float ax0 = 0, ay0 = 0, ax1 = 0, ay1 = 0, ax2 = 0, ay2 = 0, ax3 = 0, ay3 = 0;
    for (; e + 16 <= end; e += 16) {
        const u32* ep = ecol + e;
        u32 c[16];
#pragma unroll
        for (int j = 0; j < 16; j++) c[j] = ep[j];
        half2_t v[16];
#pragma unroll
        for (int j = 0; j < 16; j++)
            v[j] = *(const half2_t*)(hb + ((c[j] << 8) + loff));
#pragma unroll
        for (int j = 0; j < 16; j += 4) {
            ax0 = fmaf((float)v[j][0],     dr, ax0); ay0 = fmaf((float)v[j][1],     dr, ay0);
            ax1 = fmaf((float)v[j + 1][0], dr, ax1); ay1 = fmaf((float)v[j + 1][1], dr, ay1);
            ax2 = fmaf((float)v[j + 2][0], dr, ax2); ay2 = fmaf((float)v[j + 2][1], dr, ay2);
            ax3 = fmaf((float)v[j + 3][0], dr, ax3); ay3 = fmaf((float)v[j + 3][1], dr, ay3);
        }
    }
    for (; e < end; e += 4) {  // tail: 0-3 iterations of 4 (pdeg mult of 4)
        const u32* ep = ecol + e;
        u32 c0 = ep[0], c1 = ep[1], c2 = ep[2], c3 = ep[3];
        half2_t v0 = *(const half2_t*)(hb + ((c0 << 8) + loff));
        half2_t v1 = *(const half2_t*)(hb + ((c1 << 8) + loff));
        half2_t v2 = *(const half2_t*)(hb + ((c2 << 8) + loff));
        half2_t v3 = *(const half2_t*)(hb + ((c3 << 8) + loff));
        ax0 = fmaf((float)v0[0], dr, ax0); ay0 = fmaf((float)v0[1], dr, ay0);
        ax1 = fmaf((float)v1[0], dr, ax1); ay1 = fmaf((float)v1[1], dr, ay1);
        ax2 = fmaf((float)v2[0], dr, ax2); ay2 = fmaf((float)v2[1], dr, ay2);
        ax3 = fmaf((float)v3[0], dr, ax3); ay3 = fmaf((float)v3[1], dr, ay3);
    }
    float ax = ((ax0 + ax1) + (ax2 + ax3)) + fmaf((float)vs[0], dr, bb.x);
    float ay = ((ay0 + ay1) + (ay2 + ay3)) + fmaf((float)vs[1], dr, bb.y);
    ax = fmaxf(ax, 0.f) * dr;  // pre-scale for next layer's gather
    ay = fmaxf(ay, 0.f) * dr;
    half2_t o;
    o[0] = (f16)ax;
    o[1] = (f16)ay;
    ((half2_t*)out)[(size_t)r * 64 + lane] = o;
}

// 16 lanes per row; h3' pre-scaled; padded CSR (PGRAN=4) -> 8-batches + one
// optional 4-batch tail; uint2 descriptor + hoisted self/bias loads.
__global__ __launch_bounds__(256) void agg16_lsm(const f16* __restrict__ h3,
                                                 const u32* __restrict__ ecol,
                                                 const uint2* __restrict__ rdesc,
                                                 const float* __restrict__ dinv,
                                                 const float* __restrict__ bias,
                                                 float* __restrict__ out, int M) {
    int g = threadIdx.x >> 4, l = threadIdx.x & 15;
    int r = blockIdx.x * 16 + g;
    if (r >= M) return;
    uint2 d = rdesc[r];
    u32 beg = d.x, end = d.y;
    float dr = dinv[r];
    float bl = bias[l];
    float self = (float)h3[(size_t)r * 16 + l];
    float a0 = 0.f, a1 = 0.f, a2 = 0.f, a3 = 0.f;
    u32 e = beg;
    for (; e + 8 <= end; e += 8) {
        u32 c[8];
#pragma unroll
        for (int j = 0; j < 8; j++) c[j] = ecol[e + j];
        f16 v[8];
#pragma unroll
        for (int j = 0; j < 8; j++) v[j] = h3[(size_t)c[j] * 16 + l];
        a0 += (float)v[0] + (float)v[4];
        a1 += (float)v[1] + (float)v[5];
        a2 += (float)v[2] + (float)v[6];
        a3 += (float)v[3] + (float)v[7];
    }
    if (e < end) {  // remainder is exactly 4
        u32 c[4];
#pragma unroll
        for (int j = 0; j < 4; j++) c[j] = ecol[e + j];
        f16 v[4];
#pragma unroll
        for (int j = 0; j < 4; j++) v[j] = h3[(size_t)c[j] * 16 + l];
        a0 += (float)v[0];
        a1 += (float)v[1];
        a2 += (float)v[2];
        a3 += (float)v[3];
    }
    float acc = (((a0 + a1) + (a2 + a3)) + self) * dr + bl;
    float m = acc;
#pragma unroll
    for (int o = 8; o >= 1; o >>= 1) m = fmaxf(m, __shfl_xor(m, o, 16));
    float ex = expf(acc - m);
    float s = ex;
#pragma unroll
    for (int o = 8; o >= 1; o >>= 1) s += __shfl_xor(s, o, 16);
    out[(size_t)r * 16 + l] = acc - m - logf(s);
}

// ---------------- launch ----------------

extern "C" void kernel_launch(void* const* d_in, const int* in_sizes, int n_in,
                              void* d_out, int out_size, void* d_ws, size_t ws_size,
                              hipStream_t stream) {
    const float* x = (const float*)d_in[0];
    const int* ei = (const int*)d_in[1];
    const float* W1 = (const float*)d_in[2];
    const float* b1 = (const float*)d_in[3];
    const float* W2 = (const float*)d_in[4];
    const float* b2 = (const float*)d_in[5];
    const float* W3 = (const float*)d_in[6];
    const float* b3 = (const float*)d_in[7];
    int N = in_sizes[0] / D_IN;
    int E = in_sizes[1] / 2;

    int NBK = (N + RPB - 1) / RPB;     // 782 row-buckets (<= MAXBUCK)
    int NB = (E + CHUNK - 1) / CHUNK;  // 157 scatter blocks

    char* p = (char*)d_ws;
    auto alloc = [&](size_t bytes) -> void* {
        void* q = (void*)p;
        p += (bytes + 255) & ~(size_t)255;
        return q;
    };
    u32* bcnt = (u32*)alloc((size_t)NBK * 4);
    float* dinv = (float*)alloc((size_t)N * 4);
    uint2* rdesc = (uint2*)alloc((size_t)(N + 1) * 8);
    u32* bdata = (u32*)alloc((size_t)NBK * CAP * 4);
    u32* ecol = (u32*)alloc((size_t)NBK * PCAP * 4 + 256);
    f16* wf1h = (f16*)alloc(16384 * 2);
    f16* wf1l = (f16*)alloc(16384 * 2);
    f16* wf2h = (f16*)alloc(16384 * 2);
    f16* wf2l = (f16*)alloc(16384 * 2);
    f16* wf3h = (f16*)alloc(2048 * 2);
    f16* wf3l = (f16*)alloc(2048 * 2);
    f16* h = (f16*)alloc((size_t)(N + 1) * 128 * 2);   // +1 sentinel zero row
    f16* act = (f16*)alloc((size_t)N * 128 * 2);
    f16* h3 = (f16*)alloc((size_t)(N + 1) * 16 * 2);   // +1 sentinel zero row
    (void)ws_size; (void)n_in; (void)out_size;

    hipMemsetAsync(bcnt, 0, (size_t)NBK * 4, stream);

    scatter_k<<<NB + 18, 256, 0, stream>>>(ei, bcnt, bdata, E, N, NBK, NB,
                                           W1, W2, W3, wf1h, wf1l, wf2h, wf2l,
                                           wf3h, wf3l,
                                           h + (size_t)N * 128,
                                           h3 + (size_t)N * 16);
    finalize_k<<<NBK, 256, 0, stream>>>(bdata, bcnt, rdesc, dinv, ecol, N);

    int gb128 = (N + 127) / 128;
    int gb64 = (N + 63) / 64;
    int ab = (N + 3) / 4;
    gemm128_l1<<<gb128, 256, 0, stream>>>(x, wf1h, wf1l, dinv, h, N);
    agg128<<<ab, 256, 0, stream>>>(h, ecol, rdesc, dinv, b1, act, N);
    gemm128_l2<<<gb128, 256, 0, stream>>>(act, wf2h, wf2l, h, N);
    agg128<<<ab, 256, 0, stream>>>(h, ecol, rdesc, dinv, b2, act, N);
    gemm16<<<gb64, 256, 0, stream>>>(act, wf3h, wf3l, h3, N);
    agg16_lsm<<<(N + 15) / 16, 256, 0, stream>>>(h3, ecol, rdesc,
                                                 dinv, b3, (float*)d_out, N);
}

// Round 7
// 330.111 us; speedup vs baseline: 1.1826x; 1.0082x over previous
//
#include <hip/hip_runtime.h>

typedef unsigned int u32;
typedef _Float16 f16;
typedef __attribute__((ext_vector_type(8))) _Float16 half8;
typedef __attribute__((ext_vector_type(2))) _Float16 half2_t;
typedef __attribute__((ext_vector_type(4))) float f32x4;

#define D_IN 128
#define D_HID 128
#define D_OUT 16
#define RPB 128        // rows per bucket (lr fits in 7 bits; c < 2^20)
#define MAXBUCK 1024   // supports N <= 131072
#define CHUNK 2048     // edges per scatter block. R17: 10240 -> 2048 (relic of
                       // the deleted scan2 constraint). 782 blocks = 12 w/CU;
                       // R6 PMC showed scatter at 5.9% occupancy, 57.8us.
#define PGRAN 4        // pad each row's edge run to a multiple of 4
#define CAP 3072       // bdata capacity per bucket (mean 2046, +22 sigma)
#define PCAP 3584      // ecol capacity per bucket; >= CAP + 3*128 pad

// ---------------- preprocessing ----------------

__device__ inline int load_row(const int* ei, u32 f, int e, int E) {
    return f ? ei[e] : ei[2 * e];
}
__device__ inline int load_col(const int* ei, u32 f, int e, int E) {
    return f ? ei[E + e] : ei[2 * E + 2 * e];
}
__device__ inline int clampi(int v, int n) {
    v = v < 0 ? 0 : v;
    return v >= n ? n - 1 : v;
}

// Single scatter pass (R15) + reformat fused as 18 trailing blocks (R16).
// Scatter blocks [0,NB): per-block layout detect, LDS hist, ONE global
// atomicAdd per (bucket,block) reserve, L2-hot re-read scatter into the
// bucket's FIXED region [b*CAP, b*CAP+CAP). Record = (r&127)<<20 | c.
__global__ __launch_bounds__(256) void scatter_k(const int* __restrict__ ei,
                                                 u32* __restrict__ bcnt,
                                                 u32* __restrict__ bdata,
                                                 int E, int N, int NBK, int NB,
                                                 const float* __restrict__ W1,
                                                 const float* __restrict__ W2,
                                                 const float* __restrict__ W3,
                                                 f16* __restrict__ W1h, f16* __restrict__ W1l,
                                                 f16* __restrict__ W2h, f16* __restrict__ W2l,
                                                 f16* __restrict__ W3h, f16* __restrict__ W3l,
                                                 f16* __restrict__ hzero,
                                                 f16* __restrict__ h3zero) {
    if (blockIdx.x >= (u32)NB) {  // ---- fused reformat path ----
        int rb = blockIdx.x - NB;
        if (rb == 17) {
            int tix = threadIdx.x;
            if (tix < 128) hzero[tix] = (f16)0;
            else if (tix < 144) h3zero[tix - 128] = (f16)0;
            return;
        }
        const float* W;
        f16 *Wh, *Wl;
        int ntiles, bidx;
        if (rb < 8) { W = W1; Wh = W1h; Wl = W1l; ntiles = 8; bidx = rb; }
        else if (rb < 16) { W = W2; Wh = W2h; Wl = W2l; ntiles = 8; bidx = rb - 8; }
        else { W = W3; Wh = W3h; Wl = W3l; ntiles = 1; bidx = 0; }
        int idx = bidx * 256 + threadIdx.x;
        int total = 4 * ntiles * 64;
        if (idx >= total) return;
        int lane = idx & 63;
        int st = idx >> 6;
        int t = st % ntiles;
        int s = st / ntiles;
        int Nc = ntiles * 16;
        int n = t * 16 + (lane & 15);
        int kb = lane >> 4;
        half8 vh, vl;
#pragma unroll
        for (int j = 0; j < 8; j++) {
            float w = W[(size_t)(s * 32 + kb * 8 + j) * Nc + n];
            f16 hi = (f16)w;
            f16 lo = (f16)(w - (float)hi);
            vh[j] = hi;
            vl[j] = lo;
        }
        *(half8*)(Wh + (size_t)idx * 8) = vh;
        *(half8*)(Wl + (size_t)idx * 8) = vl;
        return;
    }
    // ---- scatter path ----
    __shared__ u32 lcnt[MAXBUCK];
    __shared__ u32 lflag;
    int tid = threadIdx.x;
    if (tid == 0) lflag = 0;
    for (int i = tid; i < NBK; i += 256) lcnt[i] = 0;
    __syncthreads();
    // layout detect: any nonzero odd 32-bit word => int32 layout
    int nw = (2 * E < 8192) ? 2 * E : 8192;
    for (int k = tid * 2 + 1; k < nw; k += 512)
        if (ei[k] != 0) atomicOr(&lflag, 1u);
    __syncthreads();
    u32 f = lflag;
    int base = blockIdx.x * CHUNK;
    int lim = base + CHUNK < E ? base + CHUNK : E;
    // pass A: count (4-way unrolled so 4 strided loads are in flight)
    for (int e = base + tid; e < lim; e += 1024) {
        int e1 = e + 256, e2 = e + 512, e3 = e + 768;
        int r0 = clampi(load_row(ei, f, e, E), N);
        int r1 = (e1 < lim) ? clampi(load_row(ei, f, e1, E), N) : -1;
        int r2 = (e2 < lim) ? clampi(load_row(ei, f, e2, E), N) : -1;
        int r3 = (e3 < lim) ? clampi(load_row(ei, f, e3, E), N) : -1;
        atomicAdd(&lcnt[(u32)r0 >> 7], 1u);
        if (r1 >= 0) atomicAdd(&lcnt[(u32)r1 >> 7], 1u);
        if (r2 >= 0) atomicAdd(&lcnt[(u32)r2 >> 7], 1u);
        if (r3 >= 0) atomicAdd(&lcnt[(u32)r3 >> 7], 1u);
    }
    __syncthreads();
    // reserve: lcnt[i] becomes this block's within-bucket write base
    for (int i = tid; i < NBK; i += 256) {
        u32 c = lcnt[i];
        lcnt[i] = c ? atomicAdd(&bcnt[i], c) : 0u;
    }
    __syncthreads();
    // pass B: scatter (chunk re-read is L2-hot)
    for (int e = base + tid; e < lim; e += 1024) {
        int e1 = e + 256, e2 = e + 512, e3 = e + 768;
        int r0 = clampi(load_row(ei, f, e, E), N);
        int c0 = clampi(load_col(ei, f, e, E), N);
        int r1 = -1, c1 = 0, r2 = -1, c2 = 0, r3 = -1, c3 = 0;
        if (e1 < lim) { r1 = clampi(load_row(ei, f, e1, E), N); c1 = clampi(load_col(ei, f, e1, E), N); }
        if (e2 < lim) { r2 = clampi(load_row(ei, f, e2, E), N); c2 = clampi(load_col(ei, f, e2, E), N); }
        if (e3 < lim) { r3 = clampi(load_row(ei, f, e3, E), N); c3 = clampi(load_col(ei, f, e3, E), N); }
        u32 b0 = (u32)r0 >> 7;
        u32 pos = atomicAdd(&lcnt[b0], 1u);
        if (pos < CAP) bdata[(size_t)b0 * CAP + pos] = ((u32)(r0 & (RPB - 1)) << 20) | (u32)c0;
        if (r1 >= 0) {
            u32 b = (u32)r1 >> 7;
            pos = atomicAdd(&lcnt[b], 1u);
            if (pos < CAP) bdata[(size_t)b * CAP + pos] = ((u32)(r1 & (RPB - 1)) << 20) | (u32)c1;
        }
        if (r2 >= 0) {
            u32 b = (u32)r2 >> 7;
            pos = atomicAdd(&lcnt[b], 1u);
            if (pos < CAP) bdata[(size_t)b * CAP + pos] = ((u32)(r2 & (RPB - 1)) << 20) | (u32)c2;
        }
        if (r3 >= 0) {
            u32 b = (u32)r3 >> 7;
            pos = atomicAdd(&lcnt[b], 1u);
            if (pos < CAP) bdata[(size_t)b * CAP + pos] = ((u32)(r3 & (RPB - 1)) << 20) | (u32)c3;
        }
    }
}

// PADDED CSR with per-row (start,end) packed in ONE uint2. Bucket b's records
// live in bdata[b*CAP .. b*CAP+min(bcnt[b],CAP)); ecol region is b*PCAP fixed.
__global__ __launch_bounds__(256) void finalize_k(const u32* __restrict__ bdata,
                                                  const u32* __restrict__ bcnt,
                                                  uint2* __restrict__ rdesc,
                                                  float* __restrict__ dinv,
                                                  u32* __restrict__ ecol,
                                                  int N) {
    __shared__ u32 smc[RPB];
    __shared__ u32 cur[RPB];
    int b = blockIdx.x;
    int tid = threadIdx.x;
    u32 cnt = bcnt[b];
    if (cnt > CAP) cnt = CAP;
    u32 s = (u32)b * CAP;
    u32 t = s + cnt;
    u32 pbase = (u32)b * PCAP;
    if (tid < RPB) smc[tid] = 0;
    __syncthreads();
    for (u32 i = s + tid; i < t; i += 256)
        atomicAdd(&smc[bdata[i] >> 20], 1u);
    __syncthreads();
    u32 deg = (tid < RPB) ? smc[tid] : 0;
    u32 pdeg = (deg + PGRAN - 1) & ~(u32)(PGRAN - 1);
    if (tid < RPB) smc[tid] = pdeg;
    __syncthreads();
    for (int off = 1; off < RPB; off <<= 1) {
        u32 tv = (tid < RPB && tid >= off) ? smc[tid - off] : 0u;
        __syncthreads();
        if (tid < RPB) smc[tid] += tv;
        __syncthreads();
    }
    u32 pexcl = (tid < RPB) ? (smc[tid] - pdeg) : 0;
    if (tid < RPB) {
        int r = b * RPB + tid;
        if (r < N) {
            rdesc[r] = make_uint2(pbase + pexcl, pbase + pexcl + pdeg);
            dinv[r] = rsqrtf((float)(deg + 1u));  // +1 self loop
        }
        cur[tid] = pbase + pexcl;
    }
    __syncthreads();
    for (u32 i = s + tid; i < t; i += 256) {
        u32 rec = bdata[i];
        u32 pos = atomicAdd(&cur[rec >> 20], 1u);
        ecol[pos] = rec & 0xFFFFFu;
    }
    __syncthreads();
    if (tid < RPB) {  // per-row pad tail -> sentinel zero-row
        u32 st = pbase + pexcl;
        for (u32 k = deg; k < pdeg; k++) ecol[st + k] = (u32)N;
    }
}

// ---------------- GEMMs (f16 MFMA 16x16x32, fp32-accurate via splits) --------
// 2 M-tiles per wave (128 rows/block); Wh/Wl staged in LDS once per block;
// each (s,t) B-fragment ds_read once feeds both tiles.

// Layer 1: A fp32 [M x 128]; 3 MFMAs/fragment; epilogue scales by dinv[rr].
__global__ __launch_bounds__(256) void gemm128_l1(const float* __restrict__ A,
                                                  const f16* __restrict__ Wh,
                                                  const f16* __restrict__ Wl,
                                                  const float* __restrict__ dinv,
                                                  f16* __restrict__ H, int M) {
    __shared__ f16 sBh[2048 * 8];  // 32KB
    __shared__ f16 sBl[2048 * 8];  // 32KB
    for (int i = threadIdx.x; i < 2048; i += 256) {
        *(half8*)(sBh + (size_t)i * 8) = *(const half8*)(Wh + (size_t)i * 8);
        *(half8*)(sBl + (size_t)i * 8) = *(const half8*)(Wl + (size_t)i * 8);
    }
    int wave = threadIdx.x >> 6, lane = threadIdx.x & 63;
    int kq = lane >> 4;
    int mb[2], ml[2];
    mb[0] = blockIdx.x * 128 + wave * 16;
    mb[1] = mb[0] + 64;
#pragma unroll
    for (int t2 = 0; t2 < 2; t2++) {
        ml[t2] = mb[t2] + (lane & 15);
        if (ml[t2] >= M) ml[t2] = M - 1;
    }
    f32x4 a0[2][4], a1[2][4];
#pragma unroll
    for (int t2 = 0; t2 < 2; t2++)
#pragma unroll
        for (int s = 0; s < 4; s++) {
            const float* ap = A + (size_t)ml[t2] * 128 + s * 32 + kq * 8;
            a0[t2][s] = *(const f32x4*)ap;
            a1[t2][s] = *(const f32x4*)(ap + 4);
        }
    f32x4 acc[2][8];
#pragma unroll
    for (int t2 = 0; t2 < 2; t2++)
#pragma unroll
        for (int t = 0; t < 8; t++) acc[t2][t] = (f32x4){0.f, 0.f, 0.f, 0.f};
    __syncthreads();
#pragma unroll
    for (int s = 0; s < 4; s++) {
        half8 ah[2], al[2];
#pragma unroll
        for (int t2 = 0; t2 < 2; t2++)
#pragma unroll
            for (int j = 0; j < 4; j++) {
                float v = a0[t2][s][j];
                f16 hi = (f16)v;
                ah[t2][j] = hi;
                al[t2][j] = (f16)(v - (float)hi);
                float w = a1[t2][s][j];
                f16 wi = (f16)w;
                ah[t2][j + 4] = wi;
                al[t2][j + 4] = (f16)(w - (float)wi);
            }
#pragma unroll
        for (int t = 0; t < 8; t++) {
            half8 bh = *(const half8*)(sBh + (size_t)((s * 8 + t) * 64 + lane) * 8);
            half8 bl = *(const half8*)(sBl + (size_t)((s * 8 + t) * 64 + lane) * 8);
            acc[0][t] = __builtin_amdgcn_mfma_f32_16x16x32_f16(ah[0], bh, acc[0][t], 0, 0, 0);
            acc[0][t] = __builtin_amdgcn_mfma_f32_16x16x32_f16(ah[0], bl, acc[0][t], 0, 0, 0);
            acc[0][t] = __builtin_amdgcn_mfma_f32_16x16x32_f16(al[0], bh, acc[0][t], 0, 0, 0);
            acc[1][t] = __builtin_amdgcn_mfma_f32_16x16x32_f16(ah[1], bh, acc[1][t], 0, 0, 0);
            acc[1][t] = __builtin_amdgcn_mfma_f32_16x16x32_f16(ah[1], bl, acc[1][t], 0, 0, 0);
            acc[1][t] = __builtin_amdgcn_mfma_f32_16x16x32_f16(al[1], bh, acc[1][t], 0, 0, 0);
        }
    }
    int coln = lane & 15;
#pragma unroll
    for (int t2 = 0; t2 < 2; t2++) {
        int rbase = mb[t2] + ((lane >> 4) << 2);
        float dsc[4];
#pragma unroll
        for (int i = 0; i < 4; i++) {
            int rr = rbase + i;
            dsc[i] = dinv[rr < M ? rr : M - 1];
        }
#pragma unroll
        for (int t = 0; t < 8; t++) {
#pragma unroll
            for (int i = 0; i < 4; i++) {
                int rr = rbase + i;
                if (rr < M) H[(size_t)rr * 128 + t * 16 + coln] = (f16)(acc[t2][t][i] * dsc[i]);
            }
        }
    }
}

// Layer 2: A f16 (pre-scaled act') [M x 128]; 2 MFMAs/fragment.
__global__ __launch_bounds__(256) void gemm128_l2(const f16* __restrict__ A,
                                                  const f16* __restrict__ Wh,
                                                  const f16* __restrict__ Wl,
                                                  f16* __restrict__ H, int M) {
    __shared__ f16 sBh[2048 * 8];
    __shared__ f16 sBl[2048 * 8];
    for (int i = threadIdx.x; i < 2048; i += 256) {
        *(half8*)(sBh + (size_t)i * 8) = *(const half8*)(Wh + (size_t)i * 8);
        *(half8*)(sBl + (size_t)i * 8) = *(const half8*)(Wl + (size_t)i * 8);
    }
    int wave = threadIdx.x >> 6, lane = threadIdx.x & 63;
    int kq = lane >> 4;
    int mb[2], ml[2];
    mb[0] = blockIdx.x * 128 + wave * 16;
    mb[1] = mb[0] + 64;
#pragma unroll
    for (int t2 = 0; t2 < 2; t2++) {
        ml[t2] = mb[t2] + (lane & 15);
        if (ml[t2] >= M) ml[t2] = M - 1;
    }
    half8 a[2][4];
#pragma unroll
    for (int t2 = 0; t2 < 2; t2++)
#pragma unroll
        for (int s = 0; s < 4; s++)
            a[t2][s] = *(const half8*)(A + (size_t)ml[t2] * 128 + s * 32 + kq * 8);
    f32x4 acc[2][8];
#pragma unroll
    for (int t2 = 0; t2 < 2; t2++)
#pragma unroll
        for (int t = 0; t < 8; t++) acc[t2][t] = (f32x4){0.f, 0.f, 0.f, 0.f};
    __syncthreads();
#pragma unroll
    for (int s = 0; s < 4; s++) {
#pragma unroll
        for (int t = 0; t < 8; t++) {
            half8 bh = *(const half8*)(sBh + (size_t)((s * 8 + t) * 64 + lane) * 8);
            half8 bl = *(const half8*)(sBl + (size_t)((s * 8 + t) * 64 + lane) * 8);
            acc[0][t] = __builtin_amdgcn_mfma_f32_16x16x32_f16(a[0][s], bh, acc[0][t], 0, 0, 0);
            acc[0][t] = __builtin_amdgcn_mfma_f32_16x16x32_f16(a[0][s], bl, acc[0][t], 0, 0, 0);
            acc[1][t] = __builtin_amdgcn_mfma_f32_16x16x32_f16(a[1][s], bh, acc[1][t], 0, 0, 0);
            acc[1][t] = __builtin_amdgcn_mfma_f32_16x16x32_f16(a[1][s], bl, acc[1][t], 0, 0, 0);
        }
    }
    int coln = lane & 15;
#pragma unroll
    for (int t2 = 0; t2 < 2; t2++) {
        int rbase = mb[t2] + ((lane >> 4) << 2);
#pragma unroll
        for (int t = 0; t < 8; t++) {
#pragma unroll
            for (int i = 0; i < 4; i++) {
                int rr = rbase + i;
                if (rr < M) H[(size_t)rr * 128 + t * 16 + coln] = (f16)acc[t2][t][i];
            }
        }
    }
}

// Layer 3: A f16 (pre-scaled) [M x 128] -> H3' f16 [M x 16].
__global__ __launch_bounds__(256) void gemm16(const f16* __restrict__ A,
                                              const f16* __restrict__ Wh,
                                              const f16* __restrict__ Wl,
                                              f16* __restrict__ H, int M) {
    __shared__ f16 sBh[256 * 8];  // 4KB
    __shared__ f16 sBl[256 * 8];  // 4KB
    if (threadIdx.x < 256) {
        int i = threadIdx.x;
        *(half8*)(sBh + (size_t)i * 8) = *(const half8*)(Wh + (size_t)i * 8);
        *(half8*)(sBl + (size_t)i * 8) = *(const half8*)(Wl + (size_t)i * 8);
    }
    int wave = threadIdx.x >> 6, lane = threadIdx.x & 63;
    int mbase = blockIdx.x * 64 + wave * 16;
    int mload = mbase + (lane & 15);
    if (mload >= M) mload = M - 1;
    int kq = lane >> 4;
    half8 a[4];
#pragma unroll
    for (int s = 0; s < 4; s++)
        a[s] = *(const half8*)(A + (size_t)mload * 128 + s * 32 + kq * 8);
    f32x4 acc = (f32x4){0.f, 0.f, 0.f, 0.f};
    __syncthreads();
#pragma unroll
    for (int s = 0; s < 4; s++) {
        half8 bh = *(const half8*)(sBh + (size_t)(s * 64 + lane) * 8);
        half8 bl = *(const half8*)(sBl + (size_t)(s * 64 + lane) * 8);
        acc = __builtin_amdgcn_mfma_f32_16x16x32_f16(a[s], bh, acc, 0, 0, 0);
        acc = __builtin_amdgcn_mfma_f32_16x16x32_f16(a[s], bl, acc, 0, 0, 0);
    }
    int coln = lane & 15;
    int rbase = mbase + ((lane >> 4) << 2);
#pragma unroll
    for (int i = 0; i < 4; i++) {
        int rr = rbase + i;
        if (rr < M) H[(size_t)rr * 16 + coln] = (f16)acc[i];
    }
}

// ---------------- aggregation ----------------
// One wave per row (R3-verified roofline schedule: ~3.87 TB/s fill, the
// random-256B-gather BW ceiling). uint2 descriptor + hoisted epilogue loads.
// DO NOT TOUCH — two alternative schedules both landed at the same fill rate.
__global__ __launch_bounds__(256) void agg128(const f16* __restrict__ h,
                                              const u32* __restrict__ ecol,
                                              const uint2* __restrict__ rdesc,
                                              const float* __restrict__ dinv,
                                              const float* __restrict__ bias,
                                              f16* __restrict__ out, int M) {
    int lane = threadIdx.x & 63;
    int wave = __builtin_amdgcn_readfirstlane(threadIdx.x >> 6);
    int r = blockIdx.x * 4 + wave;
    if (r >= M) return;
    uint2 d = rdesc[r];
    u32 e = (u32)__builtin_amdgcn_readfirstlane((int)d.x);
    u32 end = (u32)__builtin_amdgcn_readfirstlane((int)d.y);
    float dr = dinv[r];
    const char* hb = (const char*)h;
    u32 loff = (u32)lane << 2;
    float2 bb = ((const float2*)bias)[lane];
    half2_t vs = *(const half2_t*)(hb + (((u32)r << 8) + loff));
    float ax0 = 0, ay0 = 0, ax1 = 0, ay1 = 0, ax2 = 0, ay2 = 0, ax3 = 0, ay3 = 0;
    for (; e + 16 <= end; e += 16) {
        const u32* ep = ecol + e;
        u32 c[16];
#pragma unroll
        for (int j = 0; j < 16; j++) c[j] = ep[j];
        half2_t v[16];
#pragma unroll
        for (int j = 0; j < 16; j++)
            v[j] = *(const half2_t*)(hb + ((c[j] << 8) + loff));
#pragma unroll
        for (int j = 0; j < 16; j += 4) {
            ax0 = fmaf((float)v[j][0],     dr, ax0); ay0 = fmaf((float)v[j][1],     dr, ay0);
            ax1 = fmaf((float)v[j + 1][0], dr, ax1); ay1 = fmaf((float)v[j + 1][1], dr, ay1);
            ax2 = fmaf((float)v[j + 2][0], dr, ax2); ay2 = fmaf((float)v[j + 2][1], dr, ay2);
            ax3 = fmaf((float)v[j + 3][0], dr, ax3); ay3 = fmaf((float)v[j + 3][1], dr, ay3);
        }
    }
    for (; e < end; e += 4) {  // tail: 0-3 iterations of 4 (pdeg mult of 4)
        const u32* ep = ecol + e;
        u32 c0 = ep[0], c1 = ep[1], c2 = ep[2], c3 = ep[3];
        half2_t v0 = *(const half2_t*)(hb + ((c0 << 8) + loff));
        half2_t v1 = *(const half2_t*)(hb + ((c1 << 8) + loff));
        half2_t v2 = *(const half2_t*)(hb + ((c2 << 8) + loff));
        half2_t v3 = *(const half2_t*)(hb + ((c3 << 8) + loff));
        ax0 = fmaf((float)v0[0], dr, ax0); ay0 = fmaf((float)v0[1], dr, ay0);
        ax1 = fmaf((float)v1[0], dr, ax1); ay1 = fmaf((float)v1[1], dr, ay1);
        ax2 = fmaf((float)v2[0], dr, ax2); ay2 = fmaf((float)v2[1], dr, ay2);
        ax3 = fmaf((float)v3[0], dr, ax3); ay3 = fmaf((float)v3[1], dr, ay3);
    }
    float ax = ((ax0 + ax1) + (ax2 + ax3)) + fmaf((float)vs[0], dr, bb.x);
    float ay = ((ay0 + ay1) + (ay2 + ay3)) + fmaf((float)vs[1], dr, bb.y);
    ax = fmaxf(ax, 0.f) * dr;  // pre-scale for next layer's gather
    ay = fmaxf(ay, 0.f) * dr;
    half2_t o;
    o[0] = (f16)ax;
    o[1] = (f16)ay;
    ((half2_t*)out)[(size_t)r * 64 + lane] = o;
}

// 16 lanes per row; h3' pre-scaled; padded CSR (PGRAN=4) -> 8-batches + one
// optional 4-batch tail; uint2 descriptor + hoisted self/bias loads.
__global__ __launch_bounds__(256) void agg16_lsm(const f16* __restrict__ h3,
                                                 const u32* __restrict__ ecol,
                                                 const uint2* __restrict__ rdesc,
                                                 const float* __restrict__ dinv,
                                                 const float* __restrict__ bias,
                                                 float* __restrict__ out, int M) {
    int g = threadIdx.x >> 4, l = threadIdx.x & 15;
    int r = blockIdx.x * 16 + g;
    if (r >= M) return;
    uint2 d = rdesc[r];
    u32 beg = d.x, end = d.y;
    float dr = dinv[r];
    float bl = bias[l];
    float self = (float)h3[(size_t)r * 16 + l];
    float a0 = 0.f, a1 = 0.f, a2 = 0.f, a3 = 0.f;
    u32 e = beg;
    for (; e + 8 <= end; e += 8) {
        u32 c[8];
#pragma unroll
        for (int j = 0; j < 8; j++) c[j] = ecol[e + j];
        f16 v[8];
#pragma unroll
        for (int j = 0; j < 8; j++) v[j] = h3[(size_t)c[j] * 16 + l];
        a0 += (float)v[0] + (float)v[4];
        a1 += (float)v[1] + (float)v[5];
        a2 += (float)v[2] + (float)v[6];
        a3 += (float)v[3] + (float)v[7];
    }
    if (e < end) {  // remainder is exactly 4
        u32 c[4];
#pragma unroll
        for (int j = 0; j < 4; j++) c[j] = ecol[e + j];
        f16 v[4];
#pragma unroll
        for (int j = 0; j < 4; j++) v[j] = h3[(size_t)c[j] * 16 + l];
        a0 += (float)v[0];
        a1 += (float)v[1];
        a2 += (float)v[2];
        a3 += (float)v[3];
    }
    float acc = (((a0 + a1) + (a2 + a3)) + self) * dr + bl;
    float m = acc;
#pragma unroll
    for (int o = 8; o >= 1; o >>= 1) m = fmaxf(m, __shfl_xor(m, o, 16));
    float ex = expf(acc - m);
    float s = ex;
#pragma unroll
    for (int o = 8; o >= 1; o >>= 1) s += __shfl_xor(s, o, 16);
    out[(size_t)r * 16 + l] = acc - m - logf(s);
}

// ---------------- launch ----------------

extern "C" void kernel_launch(void* const* d_in, const int* in_sizes, int n_in,
                              void* d_out, int out_size, void* d_ws, size_t ws_size,
                              hipStream_t stream) {
    const float* x = (const float*)d_in[0];
    const int* ei = (const int*)d_in[1];
    const float* W1 = (const float*)d_in[2];
    const float* b1 = (const float*)d_in[3];
    const float* W2 = (const float*)d_in[4];
    const float* b2 = (const float*)d_in[5];
    const float* W3 = (const float*)d_in[6];
    const float* b3 = (const float*)d_in[7];
    int N = in_sizes[0] / D_IN;
    int E = in_sizes[1] / 2;

    int NBK = (N + RPB - 1) / RPB;     // 782 row-buckets (<= MAXBUCK)
    int NB = (E + CHUNK - 1) / CHUNK;  // 782 scatter blocks

    char* p = (char*)d_ws;
    auto alloc = [&](size_t bytes) -> void* {
        void* q = (void*)p;
        p += (bytes + 255) & ~(size_t)255;
        return q;
    };
    u32* bcnt = (u32*)alloc((size_t)NBK * 4);
    float* dinv = (float*)alloc((size_t)N * 4);
    uint2* rdesc = (uint2*)alloc((size_t)(N + 1) * 8);
    u32* bdata = (u32*)alloc((size_t)NBK * CAP * 4);
    u32* ecol = (u32*)alloc((size_t)NBK * PCAP * 4 + 256);
    f16* wf1h = (f16*)alloc(16384 * 2);
    f16* wf1l = (f16*)alloc(16384 * 2);
    f16* wf2h = (f16*)alloc(16384 * 2);
    f16* wf2l = (f16*)alloc(16384 * 2);
    f16* wf3h = (f16*)alloc(2048 * 2);
    f16* wf3l = (f16*)alloc(2048 * 2);
    f16* h = (f16*)alloc((size_t)(N + 1) * 128 * 2);   // +1 sentinel zero row
    f16* act = (f16*)alloc((size_t)N * 128 * 2);
    f16* h3 = (f16*)alloc((size_t)(N + 1) * 16 * 2);   // +1 sentinel zero row
    (void)ws_size; (void)n_in; (void)out_size;

    hipMemsetAsync(bcnt, 0, (size_t)NBK * 4, stream);

    scatter_k<<<NB + 18, 256, 0, stream>>>(ei, bcnt, bdata, E, N, NBK, NB,
                                           W1, W2, W3, wf1h, wf1l, wf2h, wf2l,
                                           wf3h, wf3l,
                                           h + (size_t)N * 128,
                                           h3 + (size_t)N * 16);
    finalize_k<<<NBK, 256, 0, stream>>>(bdata, bcnt, rdesc, dinv, ecol, N);

    int gb128 = (N + 127) / 128;
    int gb64 = (N + 63) / 64;
    int ab = (N + 3) / 4;
    gemm128_l1<<<gb128, 256, 0, stream>>>(x, wf1h, wf1l, dinv, h, N);
    agg128<<<ab, 256, 0, stream>>>(h, ecol, rdesc, dinv, b1, act, N);
    gemm128_l2<<<gb128, 256, 0, stream>>>(act, wf2h, wf2l, h, N);
    agg128<<<ab, 256, 0, stream>>>(h, ecol, rdesc, dinv, b2, act, N);
    gemm16<<<gb64, 256, 0, stream>>>(act, wf3h, wf3l, h3, N);
    agg16_lsm<<<(N + 15) / 16, 256, 0, stream>>>(h3, ecol, rdesc,
                                                 dinv, b3, (float*)d_out, N);
}